// Round 2
// baseline (5222.675 us; speedup 1.0000x reference)
//
#include <hip/hip_runtime.h>

typedef unsigned short u16;
typedef __bf16 bf16x8 __attribute__((ext_vector_type(8)));
typedef float f32x4 __attribute__((ext_vector_type(4)));

#define NLAYER 4
#define DMODEL 1024
#define DINNER 2048
#define NHEADS 64
#define CONVDIM 2304
#define XBCLD 2368
#define DPROJ 4416
#define DPROJP 4480
#define BATCH 4
#define SEQLEN 2048
#define NTOK 8192

__device__ __forceinline__ u16 f2bf(float f) {
  union { float f; unsigned u; } v; v.f = f;
  return (u16)((v.u + 0x7fffu + ((v.u >> 16) & 1u)) >> 16);
}
__device__ __forceinline__ float bf2f(u16 h) {
  union { unsigned u; float f; } v; v.u = (unsigned)h << 16; return v.f;
}

__device__ __forceinline__ float block_sum256(float v) {
  __shared__ float red[4];
  #pragma unroll
  for (int o = 32; o; o >>= 1) v += __shfl_xor(v, o);
  int t = threadIdx.x;
  if ((t & 63) == 0) red[t >> 6] = v;
  __syncthreads();
  return red[0] + red[1] + red[2] + red[3];
}

#define GLDS16(g, s) __builtin_amdgcn_global_load_lds( \
    (const __attribute__((address_space(1))) void*)(g), \
    (__attribute__((address_space(3))) void*)(s), 16, 0, 0)

// ---------------- bf16 MFMA GEMM, 128x128 tile, BK=64, double-buffered ----------------
// MODE 0: C[row*DMODEL+col] += acc (fp32, out_proj + residual)
// MODE 1: regioned bf16 write: col<2048 -> zy, col<4352 -> xbc, col<4416 -> dtraw(fp32)
template<int MODE>
__global__ __launch_bounds__(256, 2) void gemm_bf16_k(
    const u16* __restrict__ A, const u16* __restrict__ Bt,
    float* __restrict__ C, u16* __restrict__ zy, u16* __restrict__ xbc,
    float* __restrict__ dtraw, int K) {
  __shared__ __align__(16) u16 As[2][128 * 64];
  __shared__ __align__(16) u16 Bs[2][128 * 64];
  const int tid = threadIdx.x;
  const int w = tid >> 6, l = tid & 63;
  const int m0 = blockIdx.y << 7, n0 = blockIdx.x << 7;
  const int wr = (w >> 1) << 6, wc = (w & 1) << 6;
  const int l16 = l & 15, kg = l >> 4;
  const int sr = l >> 3, scol = (l & 7) << 3;
  const int nk = K >> 6;
  f32x4 acc[4][4] = {};

  auto stage = [&](int buf, int kt) {
    const size_t kb = (size_t)(kt << 6) + scol;
    #pragma unroll
    for (int i = 0; i < 4; ++i) {
      const int r = (w << 5) + (i << 3);
      GLDS16(A + (size_t)(m0 + r + sr) * K + kb, &As[buf][r << 6]);
      GLDS16(Bt + (size_t)(n0 + r + sr) * K + kb, &Bs[buf][r << 6]);
    }
  };

  stage(0, 0);
  asm volatile("s_waitcnt vmcnt(0)" ::: "memory");
  __syncthreads();

  int cur = 0;
  for (int kt = 0; kt < nk; ++kt) {
    if (kt + 1 < nk) stage(cur ^ 1, kt + 1);
    #pragma unroll
    for (int ks = 0; ks < 2; ++ks) {
      bf16x8 af[4], bfr[4];
      #pragma unroll
      for (int m = 0; m < 4; ++m)
        af[m] = *(const bf16x8*)&As[cur][((wr + (m << 4) + l16) << 6) + (ks << 5) + (kg << 3)];
      #pragma unroll
      for (int n = 0; n < 4; ++n)
        bfr[n] = *(const bf16x8*)&Bs[cur][((wc + (n << 4) + l16) << 6) + (ks << 5) + (kg << 3)];
      #pragma unroll
      for (int m = 0; m < 4; ++m)
        #pragma unroll
        for (int n = 0; n < 4; ++n)
          acc[m][n] = __builtin_amdgcn_mfma_f32_16x16x32_bf16(af[m], bfr[n], acc[m][n], 0, 0, 0);
    }
    asm volatile("s_waitcnt vmcnt(0)" ::: "memory");
    __syncthreads();
    cur ^= 1;
  }

  #pragma unroll
  for (int m = 0; m < 4; ++m) {
    const int row = m0 + wr + (m << 4) + (kg << 2);
    #pragma unroll
    for (int n = 0; n < 4; ++n) {
      const int col = n0 + wc + (n << 4) + l16;
      #pragma unroll
      for (int r = 0; r < 4; ++r) {
        const float v = acc[m][n][r];
        const size_t rr = (size_t)(row + r);
        if (MODE == 0) {
          C[rr * DMODEL + col] += v;
        } else {
          if (col < DINNER)            zy[rr * DINNER + col] = f2bf(v);
          else if (col < DINNER + CONVDIM) xbc[rr * XBCLD + (col - DINNER)] = f2bf(v);
          else if (col < DPROJ)        dtraw[rr * 64 + (col - DINNER - CONVDIM)] = v;
        }
      }
    }
  }
}

// ---------------- transpose fp32 [R,Cin] -> bf16 [Cpad,R], pad rows zeroed ----------------
__global__ __launch_bounds__(256) void transpose_cvt_k(
    const float* __restrict__ in, u16* __restrict__ out, int R, int Cin, int Cpad) {
  __shared__ float t[64][65];
  const int c0 = blockIdx.x << 6, r0 = blockIdx.y << 6;
  const int tx = threadIdx.x & 63, ty = threadIdx.x >> 6;
  #pragma unroll
  for (int i = 0; i < 16; ++i) {
    int r = ty + (i << 2);
    int cc = c0 + tx;
    t[r][tx] = (cc < Cin) ? in[(size_t)(r0 + r) * Cin + cc] : 0.f;
  }
  __syncthreads();
  #pragma unroll
  for (int i = 0; i < 16; ++i) {
    int c = ty + (i << 2);
    out[(size_t)(c0 + c) * R + r0 + tx] = f2bf(t[tx][c]);
  }
}

__global__ void copy_k(const float* __restrict__ in, float* __restrict__ out, int n4) {
  int i = blockIdx.x * blockDim.x + threadIdx.x;
  int stride = gridDim.x * blockDim.x;
  for (; i < n4; i += stride)
    *(f32x4*)&out[(size_t)i * 4] = *(const f32x4*)&in[(size_t)i * 4];
}

// ---------------- RMSNorm over 1024 fp32 -> bf16 ----------------
__global__ __launch_bounds__(256) void rmsnorm_bf16_k(
    const float* __restrict__ in, const float* __restrict__ w, u16* __restrict__ out) {
  const size_t row = blockIdx.x;
  const int t = threadIdx.x;
  f32x4 v = *(const f32x4*)&in[row * DMODEL + t * 4];
  float ss = block_sum256(v[0]*v[0] + v[1]*v[1] + v[2]*v[2] + v[3]*v[3]);
  float sc = rsqrtf(ss * (1.f / DMODEL) + 1e-5f);
  f32x4 wv = *(const f32x4*)&w[t * 4];
  ushort4 o;
  o.x = f2bf(v[0] * sc * wv[0]); o.y = f2bf(v[1] * sc * wv[1]);
  o.z = f2bf(v[2] * sc * wv[2]); o.w = f2bf(v[3] * sc * wv[3]);
  *(ushort4*)&out[row * DMODEL + t * 4] = o;
}

__global__ __launch_bounds__(256) void final_rmsnorm_k(
    const float* __restrict__ in, const float* __restrict__ w, float* __restrict__ out) {
  const size_t row = blockIdx.x;
  const int t = threadIdx.x;
  f32x4 v = *(const f32x4*)&in[row * DMODEL + t * 4];
  float ss = block_sum256(v[0]*v[0] + v[1]*v[1] + v[2]*v[2] + v[3]*v[3]);
  float sc = rsqrtf(ss * (1.f / DMODEL) + 1e-5f);
  f32x4 wv = *(const f32x4*)&w[t * 4];
  f32x4 o;
  #pragma unroll
  for (int j = 0; j < 4; ++j) o[j] = v[j] * sc * wv[j];
  *(f32x4*)&out[row * DMODEL + t * 4] = o;
}

// ---------------- causal depthwise conv(4) + silu; bf16 in [NTOK,XBCLD], bf16 out [NTOK,CONVDIM] ----------------
__global__ __launch_bounds__(256) void conv_silu_k(
    const u16* __restrict__ xbc, const float* __restrict__ cw,
    const float* __restrict__ cb, u16* __restrict__ xact) {
  const int c = (blockIdx.x << 8) + threadIdx.x;          // 0..2303
  const int b = blockIdx.y >> 8;
  const int t0 = (blockIdx.y & 255) << 3;
  const size_t rb = (size_t)b * SEQLEN + t0;
  const float w0 = cw[c*4], w1 = cw[c*4+1], w2 = cw[c*4+2], w3 = cw[c*4+3];
  const float bias = cb[c];
  const u16* src = xbc + c;
  float xm3 = t0 ? bf2f(src[(rb - 3) * XBCLD]) : 0.f;
  float xm2 = t0 ? bf2f(src[(rb - 2) * XBCLD]) : 0.f;
  float xm1 = t0 ? bf2f(src[(rb - 1) * XBCLD]) : 0.f;
  #pragma unroll
  for (int j = 0; j < 8; ++j) {
    float xc = bf2f(src[(rb + j) * XBCLD]);
    float a = bias + w0 * xm3 + w1 * xm2 + w2 * xm1 + w3 * xc;
    xact[(rb + j) * CONVDIM + c] = f2bf(a / (1.f + expf(-a)));
    xm3 = xm2; xm2 = xm1; xm1 = xc;
  }
}

// ---------------- dt = softplus(raw+bias) fp32, dA = exp(dt * -exp(A_log)) ----------------
__global__ __launch_bounds__(256) void dt_k(
    const float* __restrict__ dtraw, const float* __restrict__ dtbias,
    const float* __restrict__ alog, float* __restrict__ dtb, float* __restrict__ dab) {
  const int i = blockIdx.x * 256 + threadIdx.x;           // NTOK*64
  const int h = i & 63;
  float raw = dtraw[i] + dtbias[h];
  float dt = raw > 20.f ? raw : log1pf(expf(raw));
  float dA = expf(dt * -expf(alog[h]));
  dtb[i] = dt; dab[i] = dA;
}

// ---------------- SSM scan: 512 blocks = (b, h, p-half); 8 states/thread ----------------
__global__ __launch_bounds__(256) void scan_k(
    const u16* __restrict__ xact, const float* __restrict__ dtb,
    const float* __restrict__ dab, const float* __restrict__ Dv,
    u16* __restrict__ ybuf) {
  const int bx = blockIdx.x;
  const int b = bx >> 7, h = (bx >> 1) & 63, ph = bx & 1;
  const int p = (ph << 4) + (threadIdx.x >> 4);
  const int ng = threadIdx.x & 15;
  const size_t rowb = (size_t)b * SEQLEN;
  const float Dh = Dv[h];
  float s[8] = {};
  float dA_c, dt_c, xs_c; bf16x8 B_c, C_c;
  {
    const u16* bp = &xact[rowb * CONVDIM + 2048 + (ng << 3)];
    dA_c = dab[rowb * 64 + h]; dt_c = dtb[rowb * 64 + h];
    xs_c = bf2f(xact[rowb * CONVDIM + (h << 5) + p]);
    B_c = *(const bf16x8*)bp; C_c = *(const bf16x8*)(bp + 128);
  }
  for (int t = 0; t < SEQLEN; ++t) {
    float dA_n = 0.f, dt_n = 0.f, xs_n = 0.f; bf16x8 B_n = {}, C_n = {};
    if (t + 1 < SEQLEN) {
      const size_t r = rowb + t + 1;
      const u16* bp = &xact[r * CONVDIM + 2048 + (ng << 3)];
      dA_n = dab[r * 64 + h]; dt_n = dtb[r * 64 + h];
      xs_n = bf2f(xact[r * CONVDIM + (h << 5) + p]);
      B_n = *(const bf16x8*)bp; C_n = *(const bf16x8*)(bp + 128);
    }
    const float dtx = dt_c * xs_c;
    float y0 = 0.f, y1 = 0.f;
    #pragma unroll
    for (int j = 0; j < 8; ++j) {
      float sv = s[j] * dA_c + dtx * (float)B_c[j];
      s[j] = sv;
      if (j & 1) y1 += sv * (float)C_c[j]; else y0 += sv * (float)C_c[j];
    }
    float y = y0 + y1;
    y += __shfl_xor(y, 1); y += __shfl_xor(y, 2);
    y += __shfl_xor(y, 4); y += __shfl_xor(y, 8);
    if (ng == 0) ybuf[(rowb + t) * DINNER + (h << 5) + p] = f2bf(y + Dh * xs_c);
    dA_c = dA_n; dt_c = dt_n; xs_c = xs_n; B_c = B_n; C_c = C_n;
  }
}

// ---------------- gated RMSNorm: zy <- bf16(rmsnorm(y * silu(zy)) * gw), in place ----------------
__global__ __launch_bounds__(256) void gate_rmsnorm_k(
    const u16* __restrict__ y, u16* __restrict__ zy, const float* __restrict__ gw) {
  const size_t row = blockIdx.x;
  const int t = threadIdx.x;
  bf16x8 yv = *(const bf16x8*)&y[row * DINNER + t * 8];
  bf16x8 zv = *(const bf16x8*)&zy[row * DINNER + t * 8];
  float val[8]; float ss = 0.f;
  #pragma unroll
  for (int j = 0; j < 8; ++j) {
    float z = (float)zv[j];
    float v = (float)yv[j] * (z / (1.f + expf(-z)));
    val[j] = v; ss += v * v;
  }
  ss = block_sum256(ss);
  float sc = rsqrtf(ss * (1.f / DINNER) + 1e-5f);
  ushort4 o0, o1;
  o0.x = f2bf(val[0]*sc*gw[t*8+0]); o0.y = f2bf(val[1]*sc*gw[t*8+1]);
  o0.z = f2bf(val[2]*sc*gw[t*8+2]); o0.w = f2bf(val[3]*sc*gw[t*8+3]);
  o1.x = f2bf(val[4]*sc*gw[t*8+4]); o1.y = f2bf(val[5]*sc*gw[t*8+5]);
  o1.z = f2bf(val[6]*sc*gw[t*8+6]); o1.w = f2bf(val[7]*sc*gw[t*8+7]);
  *(ushort4*)&zy[row * DINNER + t * 8] = o0;
  *(ushort4*)&zy[row * DINNER + t * 8 + 4] = o1;
}

extern "C" void kernel_launch(void* const* d_in, const int* in_sizes, int n_in,
                              void* d_out, int out_size, void* d_ws, size_t ws_size,
                              hipStream_t stream) {
  const float* x       = (const float*)d_in[0];
  const float* W_in    = (const float*)d_in[1];
  const float* conv_w  = (const float*)d_in[2];
  const float* conv_b  = (const float*)d_in[3];
  const float* dt_bias = (const float*)d_in[4];
  const float* A_log   = (const float*)d_in[5];
  const float* Dv      = (const float*)d_in[6];
  const float* gate_w  = (const float*)d_in[7];
  const float* W_out   = (const float*)d_in[8];
  const float* block_w = (const float*)d_in[9];
  const float* final_w = (const float*)d_in[10];
  float* out = (float*)d_out;

  char* p = (char*)d_ws;
  auto alloc = [&](size_t bytes) { char* r = p; p += (bytes + 255) & ~(size_t)255; return r; };
  float* hbuf  = (float*)alloc((size_t)NTOK * DMODEL * 4);            // fp32 residual
  u16*   slabA = (u16*)  alloc((size_t)NTOK * DINNER * 2);            // hn (first half) / ybuf
  u16*   slabB = (u16*)  alloc((size_t)NTOK * DINNER * 2);            // zy -> ybf (in-place gate)
  u16*   slabC = (u16*)  alloc((size_t)NTOK * CONVDIM * 2);           // wt (transposed W) / xact
  u16*   xbc   = (u16*)  alloc((size_t)NTOK * XBCLD * 2);
  float* dtraw = (float*)alloc((size_t)NTOK * NHEADS * 4);
  float* dtb   = (float*)alloc((size_t)NTOK * NHEADS * 4);
  float* dab   = (float*)alloc((size_t)NTOK * NHEADS * 4);
  if ((size_t)(p - (char*)d_ws) > ws_size) return;  // zero output signature: absmax ~5.47

  u16* hn   = slabA;
  u16* ybuf = slabA;
  u16* wt   = slabC;
  u16* xact = slabC;

  copy_k<<<2048, 256, 0, stream>>>(x, hbuf, NTOK * DMODEL / 4);

  for (int l = 0; l < NLAYER; ++l) {
    rmsnorm_bf16_k<<<NTOK, 256, 0, stream>>>(hbuf, block_w + l * DMODEL, hn);
    transpose_cvt_k<<<dim3(DPROJP/64, DMODEL/64), 256, 0, stream>>>(
        W_in + (size_t)l * DMODEL * DPROJ, wt, DMODEL, DPROJ, DPROJP);
    gemm_bf16_k<1><<<dim3(DPROJP/128, NTOK/128), 256, 0, stream>>>(
        hn, wt, nullptr, slabB, xbc, dtraw, DMODEL);
    conv_silu_k<<<dim3(CONVDIM/256, BATCH * SEQLEN / 8), 256, 0, stream>>>(
        xbc, conv_w + (size_t)l * CONVDIM * 4, conv_b + (size_t)l * CONVDIM, xact);
    dt_k<<<NTOK * NHEADS / 256, 256, 0, stream>>>(
        dtraw, dt_bias + l * NHEADS, A_log + l * NHEADS, dtb, dab);
    scan_k<<<512, 256, 0, stream>>>(xact, dtb, dab, Dv + l * NHEADS, ybuf);
    gate_rmsnorm_k<<<NTOK, 256, 0, stream>>>(ybuf, slabB, gate_w + (size_t)l * DINNER);
    transpose_cvt_k<<<dim3(DMODEL/64, DINNER/64), 256, 0, stream>>>(
        W_out + (size_t)l * DINNER * DMODEL, wt, DINNER, DMODEL, DMODEL);
    gemm_bf16_k<0><<<dim3(DMODEL/128, NTOK/128), 256, 0, stream>>>(
        slabB, wt, hbuf, nullptr, nullptr, nullptr, DINNER);
  }
  final_rmsnorm_k<<<NTOK, 256, 0, stream>>>(hbuf, final_w, out);
}

// Round 3
// 3438.626 us; speedup vs baseline: 1.5188x; 1.5188x over previous
//
#include <hip/hip_runtime.h>

typedef unsigned short u16;
typedef __bf16 bf16x8 __attribute__((ext_vector_type(8)));
typedef float f32x4 __attribute__((ext_vector_type(4)));
typedef u16 u16x8 __attribute__((ext_vector_type(8)));

#define NLAYER 4
#define DMODEL 1024
#define DINNER 2048
#define NHEADS 64
#define CONVDIM 2304
#define XBCLD 2368
#define DPROJ 4416
#define DPROJP 4480
#define BATCH 4
#define SEQLEN 2048
#define NTOK 8192
#define TCH 32          // scan chunk (timesteps per LDS stage)

__device__ __forceinline__ u16 f2bf(float f) {
  union { float f; unsigned u; } v; v.f = f;
  return (u16)((v.u + 0x7fffu + ((v.u >> 16) & 1u)) >> 16);
}
__device__ __forceinline__ float bf2f(u16 h) {
  union { unsigned u; float f; } v; v.u = (unsigned)h << 16; return v.f;
}

__device__ __forceinline__ float block_sum256(float v) {
  __shared__ float red[4];
  #pragma unroll
  for (int o = 32; o; o >>= 1) v += __shfl_xor(v, o);
  int t = threadIdx.x;
  if ((t & 63) == 0) red[t >> 6] = v;
  __syncthreads();
  return red[0] + red[1] + red[2] + red[3];
}

#define GLDS16(g, s) __builtin_amdgcn_global_load_lds( \
    (const __attribute__((address_space(1))) void*)(g), \
    (__attribute__((address_space(3))) void*)(s), 16, 0, 0)
#define GLDS4(g, s) __builtin_amdgcn_global_load_lds( \
    (const __attribute__((address_space(1))) void*)(g), \
    (__attribute__((address_space(3))) void*)(s), 4, 0, 0)

// ---------------- bf16 MFMA GEMM, 128x128 tile, BK=64, double-buffered ----------------
// MODE 0: C[row*DMODEL+col] += acc (fp32, out_proj + residual)
// MODE 1: regioned bf16 write: col<2048 -> zy, col<4352 -> xbc, col<4416 -> dtraw(fp32)
template<int MODE>
__global__ __launch_bounds__(256, 2) void gemm_bf16_k(
    const u16* __restrict__ A, const u16* __restrict__ Bt,
    float* __restrict__ C, u16* __restrict__ zy, u16* __restrict__ xbc,
    float* __restrict__ dtraw, int K) {
  __shared__ __align__(16) u16 As[2][128 * 64];
  __shared__ __align__(16) u16 Bs[2][128 * 64];
  const int tid = threadIdx.x;
  const int w = tid >> 6, l = tid & 63;
  const int m0 = blockIdx.y << 7, n0 = blockIdx.x << 7;
  const int wr = (w >> 1) << 6, wc = (w & 1) << 6;
  const int l16 = l & 15, kg = l >> 4;
  const int sr = l >> 3, scol = (l & 7) << 3;
  const int nk = K >> 6;
  f32x4 acc[4][4] = {};

  auto stage = [&](int buf, int kt) {
    const size_t kb = (size_t)(kt << 6) + scol;
    #pragma unroll
    for (int i = 0; i < 4; ++i) {
      const int r = (w << 5) + (i << 3);
      GLDS16(A + (size_t)(m0 + r + sr) * K + kb, &As[buf][r << 6]);
      GLDS16(Bt + (size_t)(n0 + r + sr) * K + kb, &Bs[buf][r << 6]);
    }
  };

  stage(0, 0);
  asm volatile("s_waitcnt vmcnt(0)" ::: "memory");
  __syncthreads();

  int cur = 0;
  for (int kt = 0; kt < nk; ++kt) {
    if (kt + 1 < nk) stage(cur ^ 1, kt + 1);
    #pragma unroll
    for (int ks = 0; ks < 2; ++ks) {
      bf16x8 af[4], bfr[4];
      #pragma unroll
      for (int m = 0; m < 4; ++m)
        af[m] = *(const bf16x8*)&As[cur][((wr + (m << 4) + l16) << 6) + (ks << 5) + (kg << 3)];
      #pragma unroll
      for (int n = 0; n < 4; ++n)
        bfr[n] = *(const bf16x8*)&Bs[cur][((wc + (n << 4) + l16) << 6) + (ks << 5) + (kg << 3)];
      #pragma unroll
      for (int m = 0; m < 4; ++m)
        #pragma unroll
        for (int n = 0; n < 4; ++n)
          acc[m][n] = __builtin_amdgcn_mfma_f32_16x16x32_bf16(af[m], bfr[n], acc[m][n], 0, 0, 0);
    }
    asm volatile("s_waitcnt vmcnt(0)" ::: "memory");
    __syncthreads();
    cur ^= 1;
  }

  #pragma unroll
  for (int m = 0; m < 4; ++m) {
    const int row = m0 + wr + (m << 4) + (kg << 2);
    #pragma unroll
    for (int n = 0; n < 4; ++n) {
      const int col = n0 + wc + (n << 4) + l16;
      #pragma unroll
      for (int r = 0; r < 4; ++r) {
        const float v = acc[m][n][r];
        const size_t rr = (size_t)(row + r);
        if (MODE == 0) {
          C[rr * DMODEL + col] += v;
        } else {
          if (col < DINNER)            zy[rr * DINNER + col] = f2bf(v);
          else if (col < DINNER + CONVDIM) xbc[rr * XBCLD + (col - DINNER)] = f2bf(v);
          else if (col < DPROJ)        dtraw[rr * 64 + (col - DINNER - CONVDIM)] = v;
        }
      }
    }
  }
}

// ---------------- transpose fp32 [R,Cin] -> bf16 [Cpad,R], pad rows zeroed ----------------
__global__ __launch_bounds__(256) void transpose_cvt_k(
    const float* __restrict__ in, u16* __restrict__ out, int R, int Cin, int Cpad) {
  __shared__ float t[64][65];
  const int c0 = blockIdx.x << 6, r0 = blockIdx.y << 6;
  const int tx = threadIdx.x & 63, ty = threadIdx.x >> 6;
  #pragma unroll
  for (int i = 0; i < 16; ++i) {
    int r = ty + (i << 2);
    int cc = c0 + tx;
    t[r][tx] = (cc < Cin) ? in[(size_t)(r0 + r) * Cin + cc] : 0.f;
  }
  __syncthreads();
  #pragma unroll
  for (int i = 0; i < 16; ++i) {
    int c = ty + (i << 2);
    out[(size_t)(c0 + c) * R + r0 + tx] = f2bf(t[tx][c]);
  }
}

__global__ void copy_k(const float* __restrict__ in, float* __restrict__ out, int n4) {
  int i = blockIdx.x * blockDim.x + threadIdx.x;
  int stride = gridDim.x * blockDim.x;
  for (; i < n4; i += stride)
    *(f32x4*)&out[(size_t)i * 4] = *(const f32x4*)&in[(size_t)i * 4];
}

// ---------------- RMSNorm over 1024 fp32 -> bf16 ----------------
__global__ __launch_bounds__(256) void rmsnorm_bf16_k(
    const float* __restrict__ in, const float* __restrict__ w, u16* __restrict__ out) {
  const size_t row = blockIdx.x;
  const int t = threadIdx.x;
  f32x4 v = *(const f32x4*)&in[row * DMODEL + t * 4];
  float ss = block_sum256(v[0]*v[0] + v[1]*v[1] + v[2]*v[2] + v[3]*v[3]);
  float sc = rsqrtf(ss * (1.f / DMODEL) + 1e-5f);
  f32x4 wv = *(const f32x4*)&w[t * 4];
  ushort4 o;
  o.x = f2bf(v[0] * sc * wv[0]); o.y = f2bf(v[1] * sc * wv[1]);
  o.z = f2bf(v[2] * sc * wv[2]); o.w = f2bf(v[3] * sc * wv[3]);
  *(ushort4*)&out[row * DMODEL + t * 4] = o;
}

__global__ __launch_bounds__(256) void final_rmsnorm_k(
    const float* __restrict__ in, const float* __restrict__ w, float* __restrict__ out) {
  const size_t row = blockIdx.x;
  const int t = threadIdx.x;
  f32x4 v = *(const f32x4*)&in[row * DMODEL + t * 4];
  float ss = block_sum256(v[0]*v[0] + v[1]*v[1] + v[2]*v[2] + v[3]*v[3]);
  float sc = rsqrtf(ss * (1.f / DMODEL) + 1e-5f);
  f32x4 wv = *(const f32x4*)&w[t * 4];
  f32x4 o;
  #pragma unroll
  for (int j = 0; j < 4; ++j) o[j] = v[j] * sc * wv[j];
  *(f32x4*)&out[row * DMODEL + t * 4] = o;
}

// ---------------- causal depthwise conv(4) + silu; bf16 in [NTOK,XBCLD], bf16 out [NTOK,CONVDIM] ----------------
__global__ __launch_bounds__(256) void conv_silu_k(
    const u16* __restrict__ xbc, const float* __restrict__ cw,
    const float* __restrict__ cb, u16* __restrict__ xact) {
  const int c = (blockIdx.x << 8) + threadIdx.x;          // 0..2303
  const int b = blockIdx.y >> 8;
  const int t0 = (blockIdx.y & 255) << 3;
  const size_t rb = (size_t)b * SEQLEN + t0;
  const float w0 = cw[c*4], w1 = cw[c*4+1], w2 = cw[c*4+2], w3 = cw[c*4+3];
  const float bias = cb[c];
  const u16* src = xbc + c;
  float xm3 = t0 ? bf2f(src[(rb - 3) * XBCLD]) : 0.f;
  float xm2 = t0 ? bf2f(src[(rb - 2) * XBCLD]) : 0.f;
  float xm1 = t0 ? bf2f(src[(rb - 1) * XBCLD]) : 0.f;
  #pragma unroll
  for (int j = 0; j < 8; ++j) {
    float xc = bf2f(src[(rb + j) * XBCLD]);
    float a = bias + w0 * xm3 + w1 * xm2 + w2 * xm1 + w3 * xc;
    xact[(rb + j) * CONVDIM + c] = f2bf(a / (1.f + expf(-a)));
    xm3 = xm2; xm2 = xm1; xm1 = xc;
  }
}

// ---------------- dt = softplus(raw+bias) fp32, dA = exp(dt * -exp(A_log)) ----------------
__global__ __launch_bounds__(256) void dt_k(
    const float* __restrict__ dtraw, const float* __restrict__ dtbias,
    const float* __restrict__ alog, float* __restrict__ dtb, float* __restrict__ dab) {
  const int i = blockIdx.x * 256 + threadIdx.x;           // NTOK*64
  const int h = i & 63;
  float raw = dtraw[i] + dtbias[h];
  float dt = raw > 20.f ? raw : log1pf(expf(raw));
  float dA = expf(dt * -expf(alog[h]));
  dtb[i] = dt; dab[i] = dA;
}

// ---------------- SSM scan v2: LDS-chunked, double-buffered staging ----------------
// 512 blocks = (b, h, p-half); 256 thr = 16 p (tid>>4) x 16 ng (tid&15); 8 states/thread.
// Per chunk of TCH=32 steps: stage B/C (512B/token), x (32B/token), dA/dt into LDS via
// global_load_lds; hot loop reads LDS only; y accumulated in LDS, flushed coalesced.
__global__ __launch_bounds__(256) void scan_k(
    const u16* __restrict__ xact, const float* __restrict__ dtb,
    const float* __restrict__ dab, const float* __restrict__ Dv,
    u16* __restrict__ ybuf) {
  __shared__ __align__(16) u16 bc[2][TCH][256];   // [t][0..127]=B, [128..255]=C
  __shared__ __align__(16) u16 xsb[2][TCH][16];   // this block's 16 p values
  __shared__ __align__(16) float dal[2][TCH];
  __shared__ __align__(16) float dtl[2][TCH];
  __shared__ __align__(16) u16 ych[TCH][16];

  const int bx = blockIdx.x;
  const int b = bx >> 7, h = (bx >> 1) & 63, ph = bx & 1;
  const int tid = threadIdx.x;
  const int pp = tid >> 4, ng = tid & 15;
  const size_t rowb = (size_t)b * SEQLEN;
  const float Dh = Dv[h];
  const int xcol = h * 32 + ph * 16;

  auto stage = [&](int buf, int c) {
    const size_t tokb = rowb + (size_t)(c << 5);
    #pragma unroll
    for (int i = 0; i < 4; ++i) {
      const int j = (i << 8) + tid;                 // 0..1023
      GLDS16(xact + (tokb + (j >> 5)) * CONVDIM + 2048 + ((j & 31) << 3),
             (u16*)&bc[buf][0][0] + (j << 3));
    }
    if (tid < 64)
      GLDS16(xact + (tokb + (tid >> 1)) * CONVDIM + xcol + ((tid & 1) << 3),
             (u16*)&xsb[buf][0][0] + (tid << 3));
    if (tid < TCH)
      GLDS4(dab + (tokb + tid) * 64 + h, &dal[buf][0] + tid);
    else if (tid >= 64 && tid < 64 + TCH)
      GLDS4(dtb + (tokb + (tid - 64)) * 64 + h, &dtl[buf][0] + (tid - 64));
  };

  float s[8] = {};
  stage(0, 0);

  const int NCH = SEQLEN / TCH;
  for (int c = 0; c < NCH; ++c) {
    const int cur = c & 1;
    asm volatile("s_waitcnt vmcnt(0)" ::: "memory");
    __syncthreads();                                 // cur staged; ych flushed
    if (c + 1 < NCH) stage(cur ^ 1, c + 1);

    #pragma unroll 8
    for (int t = 0; t < TCH; ++t) {
      bf16x8 Bv = *(const bf16x8*)&bc[cur][t][ng << 3];
      bf16x8 Cv = *(const bf16x8*)&bc[cur][t][128 + (ng << 3)];
      const float xs = bf2f(xsb[cur][t][pp]);
      const float dA = dal[cur][t];
      const float dtv = dtl[cur][t];
      const float dtx = dtv * xs;
      float y0 = 0.f, y1 = 0.f;
      #pragma unroll
      for (int j = 0; j < 8; ++j) {
        float sv = s[j] * dA + dtx * (float)Bv[j];
        s[j] = sv;
        if (j & 1) y1 += sv * (float)Cv[j]; else y0 += sv * (float)Cv[j];
      }
      float y = y0 + y1;
      y += __shfl_xor(y, 1); y += __shfl_xor(y, 2);
      y += __shfl_xor(y, 4); y += __shfl_xor(y, 8);
      if (ng == 0) ych[t][pp] = f2bf(y + Dh * xs);
    }

    asm volatile("s_waitcnt lgkmcnt(0)" ::: "memory");
    __syncthreads();                                 // ych complete
    if (tid < 64) {                                  // coalesced y flush: 32 tok x 32B
      const size_t tok = rowb + (size_t)(c << 5) + (tid >> 1);
      u16x8 v = *(const u16x8*)&ych[tid >> 1][(tid & 1) << 3];
      *(u16x8*)&ybuf[tok * DINNER + xcol + ((tid & 1) << 3)] = v;
    }
  }
}

// ---------------- gated RMSNorm: zy <- bf16(rmsnorm(y * silu(zy)) * gw), in place ----------------
__global__ __launch_bounds__(256) void gate_rmsnorm_k(
    const u16* __restrict__ y, u16* __restrict__ zy, const float* __restrict__ gw) {
  const size_t row = blockIdx.x;
  const int t = threadIdx.x;
  bf16x8 yv = *(const bf16x8*)&y[row * DINNER + t * 8];
  bf16x8 zv = *(const bf16x8*)&zy[row * DINNER + t * 8];
  float val[8]; float ss = 0.f;
  #pragma unroll
  for (int j = 0; j < 8; ++j) {
    float z = (float)zv[j];
    float v = (float)yv[j] * (z / (1.f + expf(-z)));
    val[j] = v; ss += v * v;
  }
  ss = block_sum256(ss);
  float sc = rsqrtf(ss * (1.f / DINNER) + 1e-5f);
  ushort4 o0, o1;
  o0.x = f2bf(val[0]*sc*gw[t*8+0]); o0.y = f2bf(val[1]*sc*gw[t*8+1]);
  o0.z = f2bf(val[2]*sc*gw[t*8+2]); o0.w = f2bf(val[3]*sc*gw[t*8+3]);
  o1.x = f2bf(val[4]*sc*gw[t*8+4]); o1.y = f2bf(val[5]*sc*gw[t*8+5]);
  o1.z = f2bf(val[6]*sc*gw[t*8+6]); o1.w = f2bf(val[7]*sc*gw[t*8+7]);
  *(ushort4*)&zy[row * DINNER + t * 8] = o0;
  *(ushort4*)&zy[row * DINNER + t * 8 + 4] = o1;
}

extern "C" void kernel_launch(void* const* d_in, const int* in_sizes, int n_in,
                              void* d_out, int out_size, void* d_ws, size_t ws_size,
                              hipStream_t stream) {
  const float* x       = (const float*)d_in[0];
  const float* W_in    = (const float*)d_in[1];
  const float* conv_w  = (const float*)d_in[2];
  const float* conv_b  = (const float*)d_in[3];
  const float* dt_bias = (const float*)d_in[4];
  const float* A_log   = (const float*)d_in[5];
  const float* Dv      = (const float*)d_in[6];
  const float* gate_w  = (const float*)d_in[7];
  const float* W_out   = (const float*)d_in[8];
  const float* block_w = (const float*)d_in[9];
  const float* final_w = (const float*)d_in[10];
  float* out = (float*)d_out;

  char* p = (char*)d_ws;
  auto alloc = [&](size_t bytes) { char* r = p; p += (bytes + 255) & ~(size_t)255; return r; };
  float* hbuf  = (float*)alloc((size_t)NTOK * DMODEL * 4);            // fp32 residual
  u16*   slabA = (u16*)  alloc((size_t)NTOK * DINNER * 2);            // hn / ybuf
  u16*   slabB = (u16*)  alloc((size_t)NTOK * DINNER * 2);            // zy -> gated (in place)
  u16*   slabC = (u16*)  alloc((size_t)NTOK * CONVDIM * 2);           // wt / xact
  u16*   xbc   = (u16*)  alloc((size_t)NTOK * XBCLD * 2);
  float* dtraw = (float*)alloc((size_t)NTOK * NHEADS * 4);
  float* dtb   = (float*)alloc((size_t)NTOK * NHEADS * 4);
  float* dab   = (float*)alloc((size_t)NTOK * NHEADS * 4);
  if ((size_t)(p - (char*)d_ws) > ws_size) return;  // zero output signature: absmax ~5.47

  u16* hn   = slabA;
  u16* ybuf = slabA;
  u16* wt   = slabC;
  u16* xact = slabC;

  copy_k<<<2048, 256, 0, stream>>>(x, hbuf, NTOK * DMODEL / 4);

  for (int l = 0; l < NLAYER; ++l) {
    rmsnorm_bf16_k<<<NTOK, 256, 0, stream>>>(hbuf, block_w + l * DMODEL, hn);
    transpose_cvt_k<<<dim3(DPROJP/64, DMODEL/64), 256, 0, stream>>>(
        W_in + (size_t)l * DMODEL * DPROJ, wt, DMODEL, DPROJ, DPROJP);
    gemm_bf16_k<1><<<dim3(DPROJP/128, NTOK/128), 256, 0, stream>>>(
        hn, wt, nullptr, slabB, xbc, dtraw, DMODEL);
    conv_silu_k<<<dim3(CONVDIM/256, BATCH * SEQLEN / 8), 256, 0, stream>>>(
        xbc, conv_w + (size_t)l * CONVDIM * 4, conv_b + (size_t)l * CONVDIM, xact);
    dt_k<<<NTOK * NHEADS / 256, 256, 0, stream>>>(
        dtraw, dt_bias + l * NHEADS, A_log + l * NHEADS, dtb, dab);
    scan_k<<<512, 256, 0, stream>>>(xact, dtb, dab, Dv + l * NHEADS, ybuf);
    gate_rmsnorm_k<<<NTOK, 256, 0, stream>>>(ybuf, slabB, gate_w + (size_t)l * DINNER);
    transpose_cvt_k<<<dim3(DMODEL/64, DINNER/64), 256, 0, stream>>>(
        W_out + (size_t)l * DINNER * DMODEL, wt, DINNER, DMODEL, DMODEL);
    gemm_bf16_k<0><<<dim3(DMODEL/128, NTOK/128), 256, 0, stream>>>(
        slabB, wt, hbuf, nullptr, nullptr, nullptr, DINNER);
  }
  final_rmsnorm_k<<<NTOK, 256, 0, stream>>>(hbuf, final_w, out);
}

// Round 4
// 1900.206 us; speedup vs baseline: 2.7485x; 1.8096x over previous
//
#include <hip/hip_runtime.h>

typedef unsigned short u16;
typedef __bf16 bf16x8 __attribute__((ext_vector_type(8)));
typedef float f32x4 __attribute__((ext_vector_type(4)));
typedef u16 u16x8 __attribute__((ext_vector_type(8)));

#define NLAYER 4
#define DMODEL 1024
#define DINNER 2048
#define NHEADS 64
#define CONVDIM 2304
#define XBCLD 2368
#define DPROJ 4416
#define DPROJP 4480
#define BATCH 4
#define SEQLEN 2048
#define NTOK 8192
#define QC 64
#define NCH (SEQLEN / QC)

__device__ __forceinline__ u16 f2bf(float f) {
  union { float f; unsigned u; } v; v.f = f;
  return (u16)((v.u + 0x7fffu + ((v.u >> 16) & 1u)) >> 16);
}
__device__ __forceinline__ float bf2f(u16 h) {
  union { unsigned u; float f; } v; v.u = (unsigned)h << 16; return v.f;
}

__device__ __forceinline__ float block_sum256(float v) {
  __shared__ float red[4];
  #pragma unroll
  for (int o = 32; o; o >>= 1) v += __shfl_xor(v, o);
  int t = threadIdx.x;
  if ((t & 63) == 0) red[t >> 6] = v;
  __syncthreads();
  return red[0] + red[1] + red[2] + red[3];
}

#define GLDS16(g, s) __builtin_amdgcn_global_load_lds( \
    (const __attribute__((address_space(1))) void*)(g), \
    (__attribute__((address_space(3))) void*)(s), 16, 0, 0)

// ---------------- bf16 MFMA GEMM, 128x128 tile, BK=64, double-buffered ----------------
template<int MODE>
__global__ __launch_bounds__(256, 2) void gemm_bf16_k(
    const u16* __restrict__ A, const u16* __restrict__ Bt,
    float* __restrict__ C, u16* __restrict__ zy, u16* __restrict__ xbc,
    float* __restrict__ dtraw, int K) {
  __shared__ __align__(16) u16 As[2][128 * 64];
  __shared__ __align__(16) u16 Bs[2][128 * 64];
  const int tid = threadIdx.x;
  const int w = tid >> 6, l = tid & 63;
  const int m0 = blockIdx.y << 7, n0 = blockIdx.x << 7;
  const int wr = (w >> 1) << 6, wc = (w & 1) << 6;
  const int l16 = l & 15, kg = l >> 4;
  const int sr = l >> 3, scol = (l & 7) << 3;
  const int nk = K >> 6;
  f32x4 acc[4][4] = {};

  auto stage = [&](int buf, int kt) {
    const size_t kb = (size_t)(kt << 6) + scol;
    #pragma unroll
    for (int i = 0; i < 4; ++i) {
      const int r = (w << 5) + (i << 3);
      GLDS16(A + (size_t)(m0 + r + sr) * K + kb, &As[buf][r << 6]);
      GLDS16(Bt + (size_t)(n0 + r + sr) * K + kb, &Bs[buf][r << 6]);
    }
  };

  stage(0, 0);
  asm volatile("s_waitcnt vmcnt(0)" ::: "memory");
  __syncthreads();

  int cur = 0;
  for (int kt = 0; kt < nk; ++kt) {
    if (kt + 1 < nk) stage(cur ^ 1, kt + 1);
    #pragma unroll
    for (int ks = 0; ks < 2; ++ks) {
      bf16x8 af[4], bfr[4];
      #pragma unroll
      for (int m = 0; m < 4; ++m)
        af[m] = *(const bf16x8*)&As[cur][((wr + (m << 4) + l16) << 6) + (ks << 5) + (kg << 3)];
      #pragma unroll
      for (int n = 0; n < 4; ++n)
        bfr[n] = *(const bf16x8*)&Bs[cur][((wc + (n << 4) + l16) << 6) + (ks << 5) + (kg << 3)];
      #pragma unroll
      for (int m = 0; m < 4; ++m)
        #pragma unroll
        for (int n = 0; n < 4; ++n)
          acc[m][n] = __builtin_amdgcn_mfma_f32_16x16x32_bf16(af[m], bfr[n], acc[m][n], 0, 0, 0);
    }
    asm volatile("s_waitcnt vmcnt(0)" ::: "memory");
    __syncthreads();
    cur ^= 1;
  }

  #pragma unroll
  for (int m = 0; m < 4; ++m) {
    const int row = m0 + wr + (m << 4) + (kg << 2);
    #pragma unroll
    for (int n = 0; n < 4; ++n) {
      const int col = n0 + wc + (n << 4) + l16;
      #pragma unroll
      for (int r = 0; r < 4; ++r) {
        const float v = acc[m][n][r];
        const size_t rr = (size_t)(row + r);
        if (MODE == 0) {
          C[rr * DMODEL + col] += v;
        } else {
          if (col < DINNER)                zy[rr * DINNER + col] = f2bf(v);
          else if (col < DINNER + CONVDIM) xbc[rr * XBCLD + (col - DINNER)] = f2bf(v);
          else if (col < DPROJ)            dtraw[rr * 64 + (col - DINNER - CONVDIM)] = v;
        }
      }
    }
  }
}

// ---------------- transpose fp32 [R,Cin] -> bf16 [Cpad,R], pad rows zeroed ----------------
__global__ __launch_bounds__(256) void transpose_cvt_k(
    const float* __restrict__ in, u16* __restrict__ out, int R, int Cin, int Cpad) {
  __shared__ float t[64][65];
  const int c0 = blockIdx.x << 6, r0 = blockIdx.y << 6;
  const int tx = threadIdx.x & 63, ty = threadIdx.x >> 6;
  #pragma unroll
  for (int i = 0; i < 16; ++i) {
    int r = ty + (i << 2);
    int cc = c0 + tx;
    t[r][tx] = (cc < Cin) ? in[(size_t)(r0 + r) * Cin + cc] : 0.f;
  }
  __syncthreads();
  #pragma unroll
  for (int i = 0; i < 16; ++i) {
    int c = ty + (i << 2);
    out[(size_t)(c0 + c) * R + r0 + tx] = f2bf(t[tx][c]);
  }
}

// ---------------- bf16 transpose: in [NTOK rows, stride CONVDIM] 64x64 tiles -> out [C][NTOK] ----------------
__global__ __launch_bounds__(256) void transpose_bf16_k(
    const u16* __restrict__ in, u16* __restrict__ out) {
  __shared__ __align__(16) u16 tl[64][72];
  const int c0 = blockIdx.x << 6, r0 = blockIdx.y << 6;
  const int tid = threadIdx.x;
  #pragma unroll
  for (int i = 0; i < 2; ++i) {
    int row = (tid >> 3) + (i << 5);
    int cs = tid & 7;
    *(int4*)&tl[row][cs << 3] =
        *(const int4*)&in[(size_t)(r0 + row) * CONVDIM + c0 + (cs << 3)];
  }
  __syncthreads();
  #pragma unroll
  for (int p = 0; p < 2; ++p) {
    int slot = tid + (p << 8);
    int c = slot >> 3, tb = slot & 7;
    u16x8 v;
    #pragma unroll
    for (int j = 0; j < 8; ++j) v[j] = tl[(tb << 3) + j][c];
    *(u16x8*)&out[(size_t)(c0 + c) * NTOK + r0 + (tb << 3)] = v;
  }
}

__global__ void copy_k(const float* __restrict__ in, float* __restrict__ out, int n4) {
  int i = blockIdx.x * blockDim.x + threadIdx.x;
  int stride = gridDim.x * blockDim.x;
  for (; i < n4; i += stride)
    *(f32x4*)&out[(size_t)i * 4] = *(const f32x4*)&in[(size_t)i * 4];
}

// ---------------- RMSNorm over 1024 fp32 -> bf16 ----------------
__global__ __launch_bounds__(256) void rmsnorm_bf16_k(
    const float* __restrict__ in, const float* __restrict__ w, u16* __restrict__ out) {
  const size_t row = blockIdx.x;
  const int t = threadIdx.x;
  f32x4 v = *(const f32x4*)&in[row * DMODEL + t * 4];
  float ss = block_sum256(v[0]*v[0] + v[1]*v[1] + v[2]*v[2] + v[3]*v[3]);
  float sc = rsqrtf(ss * (1.f / DMODEL) + 1e-5f);
  f32x4 wv = *(const f32x4*)&w[t * 4];
  ushort4 o;
  o.x = f2bf(v[0] * sc * wv[0]); o.y = f2bf(v[1] * sc * wv[1]);
  o.z = f2bf(v[2] * sc * wv[2]); o.w = f2bf(v[3] * sc * wv[3]);
  *(ushort4*)&out[row * DMODEL + t * 4] = o;
}

__global__ __launch_bounds__(256) void final_rmsnorm_k(
    const float* __restrict__ in, const float* __restrict__ w, float* __restrict__ out) {
  const size_t row = blockIdx.x;
  const int t = threadIdx.x;
  f32x4 v = *(const f32x4*)&in[row * DMODEL + t * 4];
  float ss = block_sum256(v[0]*v[0] + v[1]*v[1] + v[2]*v[2] + v[3]*v[3]);
  float sc = rsqrtf(ss * (1.f / DMODEL) + 1e-5f);
  f32x4 wv = *(const f32x4*)&w[t * 4];
  f32x4 o;
  #pragma unroll
  for (int j = 0; j < 4; ++j) o[j] = v[j] * sc * wv[j];
  *(f32x4*)&out[row * DMODEL + t * 4] = o;
}

// ---------------- causal depthwise conv(4) + silu ----------------
__global__ __launch_bounds__(256) void conv_silu_k(
    const u16* __restrict__ xbc, const float* __restrict__ cw,
    const float* __restrict__ cb, u16* __restrict__ xact) {
  const int c = (blockIdx.x << 8) + threadIdx.x;
  const int b = blockIdx.y >> 8;
  const int t0 = (blockIdx.y & 255) << 3;
  const size_t rb = (size_t)b * SEQLEN + t0;
  const float w0 = cw[c*4], w1 = cw[c*4+1], w2 = cw[c*4+2], w3 = cw[c*4+3];
  const float bias = cb[c];
  const u16* src = xbc + c;
  float xm3 = t0 ? bf2f(src[(rb - 3) * XBCLD]) : 0.f;
  float xm2 = t0 ? bf2f(src[(rb - 2) * XBCLD]) : 0.f;
  float xm1 = t0 ? bf2f(src[(rb - 1) * XBCLD]) : 0.f;
  #pragma unroll
  for (int j = 0; j < 8; ++j) {
    float xc = bf2f(src[(rb + j) * XBCLD]);
    float a = bias + w0 * xm3 + w1 * xm2 + w2 * xm1 + w3 * xc;
    xact[(rb + j) * CONVDIM + c] = f2bf(a / (1.f + expf(-a)));
    xm3 = xm2; xm2 = xm1; xm1 = xc;
  }
}

// ---------------- SSD chunked scan: 256 blocks = (b,h), 4 waves, Q=64 chunks ----------------
// Per chunk: G^T = B·C^T (MFMA); P = G*exp(a_t-a_s)*dt_s (s<=t); Y = P·X + exp(a_t)·C·H + D·x;
// H = exp(a63)·H + B^T·(X*fac). H lives in per-wave accumulators across chunks.
__global__ __launch_bounds__(256) void ssd_k(
    const u16* __restrict__ xact, const u16* __restrict__ XT,
    const u16* __restrict__ BT, const float* __restrict__ dtraw,
    const float* __restrict__ dt_bias, const float* __restrict__ A_log,
    const float* __restrict__ Dv, u16* __restrict__ ybuf) {
  __shared__ __align__(16) u16 Cs[64 * 136];
  __shared__ __align__(16) u16 R1[128 * 72];   // Brow[64][136] -> BsT[128][72]
  __shared__ __align__(16) u16 Pl[64 * 72];
  __shared__ __align__(16) u16 Xt[32 * 72];
  __shared__ __align__(16) u16 Hb[32 * 136];
  __shared__ float cums[64], dts_l[64], fac[64];

  const int tid = threadIdx.x;
  const int w = tid >> 6, l = tid & 63, l16 = l & 15, kg = l >> 4;
  const int b = blockIdx.x >> 6, h = blockIdx.x & 63;
  const size_t rowb = (size_t)b * SEQLEN;
  const float expA = __expf(A_log[h]);
  const float bias = dt_bias[h];
  const float Dh = Dv[h];
  const int mi = w >> 1, njb = (w & 1) << 2;
  const int srow = tid >> 2, sseg = tid & 3;
  const int xrow = tid >> 3, xseg = tid & 7;

  f32x4 hacc[4] = {};

  for (int ch = 0; ch < NCH; ++ch) {
    const size_t tokb = rowb + ((size_t)ch << 6);
    // (a) issue global loads into regs + dt/prefix (no LDS yet)
    int4 creg[4], breg[4];
    #pragma unroll
    for (int i = 0; i < 4; ++i) {
      creg[i] = *(const int4*)&xact[(tokb + srow) * CONVDIM + 2176 + (sseg << 5) + (i << 3)];
      breg[i] = *(const int4*)&xact[(tokb + srow) * CONVDIM + 2048 + (sseg << 5) + (i << 3)];
    }
    int4 xreg = *(const int4*)&XT[(size_t)(h * 32 + xrow) * NTOK + tokb + (xseg << 3)];
    float rawv = dtraw[(tokb + l) * 64 + h] + bias;
    float dtv = rawv > 20.f ? rawv : log1pf(__expf(rawv));
    float la = -dtv * expA;
    float cv = la;
    #pragma unroll
    for (int d = 1; d < 64; d <<= 1) {
      float o = __shfl_up(cv, d);
      if (l >= d) cv += o;
    }
    const float a63 = __shfl(cv, 63);

    __syncthreads();  // S0: prev chunk consumers done
    // (b) LDS writes
    #pragma unroll
    for (int i = 0; i < 4; ++i) {
      *(int4*)&Cs[srow * 136 + (sseg << 5) + (i << 3)] = creg[i];
      *(int4*)&R1[srow * 136 + (sseg << 5) + (i << 3)] = breg[i];
    }
    *(int4*)&Xt[xrow * 72 + (xseg << 3)] = xreg;
    if (tid < 64) { cums[l] = cv; dts_l[l] = dtv; fac[l] = dtv * __expf(a63 - cv); }
    #pragma unroll
    for (int q = 0; q < 4; ++q)
      #pragma unroll
      for (int r = 0; r < 4; ++r)
        Hb[(mi * 16 + kg * 4 + r) * 136 + ((njb + q) << 4) + l16] = f2bf(hacc[q][r]);
    __syncthreads();  // S1

    // (f) G^T = B·C^T  (wave w owns s-strip w; tiles j>=w)
    f32x4 gacc[4] = {};
    #pragma unroll
    for (int ks = 0; ks < 4; ++ks) {
      bf16x8 ab = *(const bf16x8*)&R1[(w * 16 + l16) * 136 + (ks << 5) + (kg << 3)];
      #pragma unroll
      for (int j = 0; j < 4; ++j)
        if (j >= w) {
          bf16x8 bc = *(const bf16x8*)&Cs[(j * 16 + l16) * 136 + (ks << 5) + (kg << 3)];
          gacc[j] = __builtin_amdgcn_mfma_f32_16x16x32_bf16(ab, bc, gacc[j], 0, 0, 0);
        }
    }
    // (g) P[t][s]
    float c_s[4], d_s[4];
    #pragma unroll
    for (int r = 0; r < 4; ++r) {
      c_s[r] = cums[w * 16 + kg * 4 + r];
      d_s[r] = dts_l[w * 16 + kg * 4 + r];
    }
    #pragma unroll
    for (int j = 0; j < 4; ++j) {
      float c_t = cums[j * 16 + l16];
      #pragma unroll
      for (int r = 0; r < 4; ++r) {
        int s = w * 16 + kg * 4 + r, t = j * 16 + l16;
        float v = (s <= t) ? gacc[j][r] * __expf(c_t - c_s[r]) * d_s[r] : 0.f;
        Pl[t * 72 + s] = f2bf(v);
      }
    }
    __syncthreads();  // S2

    // issue BsT global loads early (consumed after S3)
    int4 btreg[4];
    #pragma unroll
    for (int i = 0; i < 4; ++i) {
      int sl = ((tid & 1) << 2) + i;
      btreg[i] = *(const int4*)&BT[(size_t)(tid >> 1) * NTOK + tokb + (sl << 3)];
    }

    // (i) Y = P·X + exp(a_t)·C·H + D·x
    f32x4 y1[2] = {}, y2[2] = {};
    const int nks = (w >= 2) ? 2 : 1;
    for (int ks = 0; ks < nks; ++ks) {
      bf16x8 ap = *(const bf16x8*)&Pl[(w * 16 + l16) * 72 + (ks << 5) + (kg << 3)];
      #pragma unroll
      for (int pj = 0; pj < 2; ++pj) {
        bf16x8 bx = *(const bf16x8*)&Xt[(pj * 16 + l16) * 72 + (ks << 5) + (kg << 3)];
        y1[pj] = __builtin_amdgcn_mfma_f32_16x16x32_bf16(ap, bx, y1[pj], 0, 0, 0);
      }
    }
    #pragma unroll
    for (int ks = 0; ks < 4; ++ks) {
      bf16x8 ac = *(const bf16x8*)&Cs[(w * 16 + l16) * 136 + (ks << 5) + (kg << 3)];
      #pragma unroll
      for (int pj = 0; pj < 2; ++pj) {
        bf16x8 bh = *(const bf16x8*)&Hb[(pj * 16 + l16) * 136 + (ks << 5) + (kg << 3)];
        y2[pj] = __builtin_amdgcn_mfma_f32_16x16x32_bf16(ac, bh, y2[pj], 0, 0, 0);
      }
    }
    #pragma unroll
    for (int r = 0; r < 4; ++r) {
      const int t = w * 16 + kg * 4 + r;
      const float et = __expf(cums[t]);
      #pragma unroll
      for (int pj = 0; pj < 2; ++pj) {
        const int p = pj * 16 + l16;
        float xv = bf2f(Xt[p * 72 + t]);
        float yv = y1[pj][r] + et * y2[pj][r] + Dh * xv;
        ybuf[(tokb + t) * DINNER + (h << 5) + p] = f2bf(yv);
      }
    }
    __syncthreads();  // S3 (Xt/P/R1 reads done)

    // (l) BsT store + Xt in-place scale
    #pragma unroll
    for (int i = 0; i < 4; ++i) {
      int sl = ((tid & 1) << 2) + i;
      *(int4*)&R1[(tid >> 1) * 72 + (sl << 3)] = btreg[i];
    }
    {
      bf16x8 xv = *(const bf16x8*)&Xt[xrow * 72 + (xseg << 3)];
      u16x8 xo;
      #pragma unroll
      for (int jj = 0; jj < 8; ++jj)
        xo[jj] = f2bf((float)xv[jj] * fac[(xseg << 3) + jj]);
      *(u16x8*)&Xt[xrow * 72 + (xseg << 3)] = xo;
    }
    __syncthreads();  // S4

    // (n) H = exp(a63)·H + B^T·Xsc   (acc layout: H_T[p][n])
    const float g63 = __expf(a63);
    #pragma unroll
    for (int q = 0; q < 4; ++q)
      #pragma unroll
      for (int r = 0; r < 4; ++r) hacc[q][r] *= g63;
    #pragma unroll
    for (int ks = 0; ks < 2; ++ks) {
      bf16x8 ax = *(const bf16x8*)&Xt[(mi * 16 + l16) * 72 + (ks << 5) + (kg << 3)];
      #pragma unroll
      for (int q = 0; q < 4; ++q) {
        bf16x8 bb = *(const bf16x8*)&R1[(((njb + q) << 4) + l16) * 72 + (ks << 5) + (kg << 3)];
        hacc[q] = __builtin_amdgcn_mfma_f32_16x16x32_bf16(ax, bb, hacc[q], 0, 0, 0);
      }
    }
  }
}

// ---------------- gated RMSNorm in place ----------------
__global__ __launch_bounds__(256) void gate_rmsnorm_k(
    const u16* __restrict__ y, u16* __restrict__ zy, const float* __restrict__ gw) {
  const size_t row = blockIdx.x;
  const int t = threadIdx.x;
  bf16x8 yv = *(const bf16x8*)&y[row * DINNER + t * 8];
  bf16x8 zv = *(const bf16x8*)&zy[row * DINNER + t * 8];
  float val[8]; float ss = 0.f;
  #pragma unroll
  for (int j = 0; j < 8; ++j) {
    float z = (float)zv[j];
    float v = (float)yv[j] * (z / (1.f + expf(-z)));
    val[j] = v; ss += v * v;
  }
  ss = block_sum256(ss);
  float sc = rsqrtf(ss * (1.f / DINNER) + 1e-5f);
  ushort4 o0, o1;
  o0.x = f2bf(val[0]*sc*gw[t*8+0]); o0.y = f2bf(val[1]*sc*gw[t*8+1]);
  o0.z = f2bf(val[2]*sc*gw[t*8+2]); o0.w = f2bf(val[3]*sc*gw[t*8+3]);
  o1.x = f2bf(val[4]*sc*gw[t*8+4]); o1.y = f2bf(val[5]*sc*gw[t*8+5]);
  o1.z = f2bf(val[6]*sc*gw[t*8+6]); o1.w = f2bf(val[7]*sc*gw[t*8+7]);
  *(ushort4*)&zy[row * DINNER + t * 8] = o0;
  *(ushort4*)&zy[row * DINNER + t * 8 + 4] = o1;
}

extern "C" void kernel_launch(void* const* d_in, const int* in_sizes, int n_in,
                              void* d_out, int out_size, void* d_ws, size_t ws_size,
                              hipStream_t stream) {
  const float* x       = (const float*)d_in[0];
  const float* W_in    = (const float*)d_in[1];
  const float* conv_w  = (const float*)d_in[2];
  const float* conv_b  = (const float*)d_in[3];
  const float* dt_bias = (const float*)d_in[4];
  const float* A_log   = (const float*)d_in[5];
  const float* Dv      = (const float*)d_in[6];
  const float* gate_w  = (const float*)d_in[7];
  const float* W_out   = (const float*)d_in[8];
  const float* block_w = (const float*)d_in[9];
  const float* final_w = (const float*)d_in[10];
  float* out = (float*)d_out;

  char* p = (char*)d_ws;
  auto alloc = [&](size_t bytes) { char* r = p; p += (bytes + 255) & ~(size_t)255; return r; };
  float* hbuf  = (float*)alloc((size_t)NTOK * DMODEL * 4);
  u16*   slabA = (u16*)  alloc((size_t)NTOK * DINNER * 2);    // hn / ybuf
  u16*   slabB = (u16*)  alloc((size_t)NTOK * DINNER * 2);    // zy (gate in place)
  u16*   slabC = (u16*)  alloc((size_t)NTOK * CONVDIM * 2);   // wt / xact
  u16*   xbcXT = (u16*)  alloc((size_t)NTOK * XBCLD * 2);     // xbc -> XT overlay
  float* dtraw = (float*)alloc((size_t)NTOK * NHEADS * 4);
  u16*   BT    = (u16*)  alloc((size_t)128 * NTOK * 2);
  if ((size_t)(p - (char*)d_ws) > ws_size) return;  // zero output signature: absmax ~5.47

  u16* hn   = slabA;
  u16* ybuf = slabA;
  u16* wt   = slabC;
  u16* xact = slabC;
  u16* xbc  = xbcXT;
  u16* XT   = xbcXT;   // overlays xbc after conv

  copy_k<<<2048, 256, 0, stream>>>(x, hbuf, NTOK * DMODEL / 4);

  for (int l = 0; l < NLAYER; ++l) {
    rmsnorm_bf16_k<<<NTOK, 256, 0, stream>>>(hbuf, block_w + l * DMODEL, hn);
    transpose_cvt_k<<<dim3(DPROJP/64, DMODEL/64), 256, 0, stream>>>(
        W_in + (size_t)l * DMODEL * DPROJ, wt, DMODEL, DPROJ, DPROJP);
    gemm_bf16_k<1><<<dim3(DPROJP/128, NTOK/128), 256, 0, stream>>>(
        hn, wt, nullptr, slabB, xbc, dtraw, DMODEL);
    conv_silu_k<<<dim3(CONVDIM/256, BATCH * SEQLEN / 8), 256, 0, stream>>>(
        xbc, conv_w + (size_t)l * CONVDIM * 4, conv_b + (size_t)l * CONVDIM, xact);
    transpose_bf16_k<<<dim3(DINNER/64, NTOK/64), 256, 0, stream>>>(xact, XT);
    transpose_bf16_k<<<dim3(2, NTOK/64), 256, 0, stream>>>(xact + DINNER, BT);
    ssd_k<<<BATCH * NHEADS, 256, 0, stream>>>(
        xact, XT, BT, dtraw, dt_bias + l * NHEADS, A_log + l * NHEADS,
        Dv + l * NHEADS, ybuf);
    gate_rmsnorm_k<<<NTOK, 256, 0, stream>>>(ybuf, slabB, gate_w + (size_t)l * DINNER);
    transpose_cvt_k<<<dim3(DMODEL/64, DINNER/64), 256, 0, stream>>>(
        W_out + (size_t)l * DINNER * DMODEL, wt, DINNER, DMODEL, DMODEL);
    gemm_bf16_k<0><<<dim3(DMODEL/128, NTOK/128), 256, 0, stream>>>(
        slabB, wt, hbuf, nullptr, nullptr, nullptr, DINNER);
  }
  final_rmsnorm_k<<<NTOK, 256, 0, stream>>>(hbuf, final_w, out);
}

// Round 5
// 1702.860 us; speedup vs baseline: 3.0670x; 1.1159x over previous
//
#include <hip/hip_runtime.h>

typedef unsigned short u16;
typedef __bf16 bf16x8 __attribute__((ext_vector_type(8)));
typedef float f32x4 __attribute__((ext_vector_type(4)));
typedef u16 u16x8 __attribute__((ext_vector_type(8)));

#define NLAYER 4
#define DMODEL 1024
#define DINNER 2048
#define NHEADS 64
#define CONVDIM 2304
#define XBCLD 2368
#define DPROJ 4416
#define DPROJP 4480
#define BATCH 4
#define SEQLEN 2048
#define NTOK 8192
#define QC 64
#define NCH (SEQLEN / QC)

__device__ __forceinline__ u16 f2bf(float f) {
  union { float f; unsigned u; } v; v.f = f;
  return (u16)((v.u + 0x7fffu + ((v.u >> 16) & 1u)) >> 16);
}
__device__ __forceinline__ float bf2f(u16 h) {
  union { unsigned u; float f; } v; v.u = (unsigned)h << 16; return v.f;
}

__device__ __forceinline__ float block_sum256(float v) {
  __shared__ float red[4];
  #pragma unroll
  for (int o = 32; o; o >>= 1) v += __shfl_xor(v, o);
  int t = threadIdx.x;
  if ((t & 63) == 0) red[t >> 6] = v;
  __syncthreads();
  return red[0] + red[1] + red[2] + red[3];
}

// XOR granule swizzle: row-major [R][128] / [R][64] u16 tiles, 8-u16 (16B) granules.
__device__ __forceinline__ int swz128(int row, int g) { return (row << 7) + (((g ^ (row & 7)) << 3)); }
__device__ __forceinline__ int swz64(int row, int g)  { return (row << 6) + (((g ^ (row & 7)) << 3)); }

#define GLDS16(g, s) __builtin_amdgcn_global_load_lds( \
    (const __attribute__((address_space(1))) void*)(g), \
    (__attribute__((address_space(3))) void*)(s), 16, 0, 0)

// ---------------- bf16 MFMA GEMM, 128x128 tile, BK=64, double-buffered ----------------
template<int MODE>
__global__ __launch_bounds__(256, 2) void gemm_bf16_k(
    const u16* __restrict__ A, const u16* __restrict__ Bt,
    float* __restrict__ C, u16* __restrict__ zy, u16* __restrict__ xbc,
    float* __restrict__ dtraw, int K) {
  __shared__ __align__(16) u16 As[2][128 * 64];
  __shared__ __align__(16) u16 Bs[2][128 * 64];
  const int tid = threadIdx.x;
  const int w = tid >> 6, l = tid & 63;
  const int m0 = blockIdx.y << 7, n0 = blockIdx.x << 7;
  const int wr = (w >> 1) << 6, wc = (w & 1) << 6;
  const int l16 = l & 15, kg = l >> 4;
  const int sr = l >> 3, scol = (l & 7) << 3;
  const int nk = K >> 6;
  f32x4 acc[4][4] = {};

  auto stage = [&](int buf, int kt) {
    const size_t kb = (size_t)(kt << 6) + scol;
    #pragma unroll
    for (int i = 0; i < 4; ++i) {
      const int r = (w << 5) + (i << 3);
      GLDS16(A + (size_t)(m0 + r + sr) * K + kb, &As[buf][r << 6]);
      GLDS16(Bt + (size_t)(n0 + r + sr) * K + kb, &Bs[buf][r << 6]);
    }
  };

  stage(0, 0);
  asm volatile("s_waitcnt vmcnt(0)" ::: "memory");
  __syncthreads();

  int cur = 0;
  for (int kt = 0; kt < nk; ++kt) {
    if (kt + 1 < nk) stage(cur ^ 1, kt + 1);
    #pragma unroll
    for (int ks = 0; ks < 2; ++ks) {
      bf16x8 af[4], bfr[4];
      #pragma unroll
      for (int m = 0; m < 4; ++m)
        af[m] = *(const bf16x8*)&As[cur][((wr + (m << 4) + l16) << 6) + (ks << 5) + (kg << 3)];
      #pragma unroll
      for (int n = 0; n < 4; ++n)
        bfr[n] = *(const bf16x8*)&Bs[cur][((wc + (n << 4) + l16) << 6) + (ks << 5) + (kg << 3)];
      #pragma unroll
      for (int m = 0; m < 4; ++m)
        #pragma unroll
        for (int n = 0; n < 4; ++n)
          acc[m][n] = __builtin_amdgcn_mfma_f32_16x16x32_bf16(af[m], bfr[n], acc[m][n], 0, 0, 0);
    }
    asm volatile("s_waitcnt vmcnt(0)" ::: "memory");
    __syncthreads();
    cur ^= 1;
  }

  #pragma unroll
  for (int m = 0; m < 4; ++m) {
    const int row = m0 + wr + (m << 4) + (kg << 2);
    #pragma unroll
    for (int n = 0; n < 4; ++n) {
      const int col = n0 + wc + (n << 4) + l16;
      #pragma unroll
      for (int r = 0; r < 4; ++r) {
        const float v = acc[m][n][r];
        const size_t rr = (size_t)(row + r);
        if (MODE == 0) {
          C[rr * DMODEL + col] += v;
        } else {
          if (col < DINNER)                zy[rr * DINNER + col] = f2bf(v);
          else if (col < DINNER + CONVDIM) xbc[rr * XBCLD + (col - DINNER)] = f2bf(v);
          else if (col < DPROJ)            dtraw[rr * 64 + (col - DINNER - CONVDIM)] = v;
        }
      }
    }
  }
}

// ---------------- transpose fp32 [R,Cin] -> bf16 [Cpad,R], pad rows zeroed ----------------
__global__ __launch_bounds__(256) void transpose_cvt_k(
    const float* __restrict__ in, u16* __restrict__ out, int R, int Cin, int Cpad) {
  __shared__ float t[64][65];
  const int c0 = blockIdx.x << 6, r0 = blockIdx.y << 6;
  const int tx = threadIdx.x & 63, ty = threadIdx.x >> 6;
  #pragma unroll
  for (int i = 0; i < 16; ++i) {
    int r = ty + (i << 2);
    int cc = c0 + tx;
    t[r][tx] = (cc < Cin) ? in[(size_t)(r0 + r) * Cin + cc] : 0.f;
  }
  __syncthreads();
  #pragma unroll
  for (int i = 0; i < 16; ++i) {
    int c = ty + (i << 2);
    out[(size_t)(c0 + c) * R + r0 + tx] = f2bf(t[tx][c]);
  }
}

// ---------------- bf16 transpose: in [NTOK rows, stride CONVDIM] -> out [C][NTOK] ----------------
__global__ __launch_bounds__(256) void transpose_bf16_k(
    const u16* __restrict__ in, u16* __restrict__ out) {
  __shared__ __align__(16) u16 tl[64][72];
  const int c0 = blockIdx.x << 6, r0 = blockIdx.y << 6;
  const int tid = threadIdx.x;
  #pragma unroll
  for (int i = 0; i < 2; ++i) {
    int row = (tid >> 3) + (i << 5);
    int cs = tid & 7;
    *(int4*)&tl[row][cs << 3] =
        *(const int4*)&in[(size_t)(r0 + row) * CONVDIM + c0 + (cs << 3)];
  }
  __syncthreads();
  #pragma unroll
  for (int p = 0; p < 2; ++p) {
    int slot = tid + (p << 8);
    int c = slot >> 3, tb = slot & 7;
    u16x8 v;
    #pragma unroll
    for (int j = 0; j < 8; ++j) v[j] = tl[(tb << 3) + j][c];
    *(u16x8*)&out[(size_t)(c0 + c) * NTOK + r0 + (tb << 3)] = v;
  }
}

__global__ void copy_k(const float* __restrict__ in, float* __restrict__ out, int n4) {
  int i = blockIdx.x * blockDim.x + threadIdx.x;
  int stride = gridDim.x * blockDim.x;
  for (; i < n4; i += stride)
    *(f32x4*)&out[(size_t)i * 4] = *(const f32x4*)&in[(size_t)i * 4];
}

// ---------------- RMSNorm over 1024 fp32 -> bf16 ----------------
__global__ __launch_bounds__(256) void rmsnorm_bf16_k(
    const float* __restrict__ in, const float* __restrict__ w, u16* __restrict__ out) {
  const size_t row = blockIdx.x;
  const int t = threadIdx.x;
  f32x4 v = *(const f32x4*)&in[row * DMODEL + t * 4];
  float ss = block_sum256(v[0]*v[0] + v[1]*v[1] + v[2]*v[2] + v[3]*v[3]);
  float sc = rsqrtf(ss * (1.f / DMODEL) + 1e-5f);
  f32x4 wv = *(const f32x4*)&w[t * 4];
  ushort4 o;
  o.x = f2bf(v[0] * sc * wv[0]); o.y = f2bf(v[1] * sc * wv[1]);
  o.z = f2bf(v[2] * sc * wv[2]); o.w = f2bf(v[3] * sc * wv[3]);
  *(ushort4*)&out[row * DMODEL + t * 4] = o;
}

__global__ __launch_bounds__(256) void final_rmsnorm_k(
    const float* __restrict__ in, const float* __restrict__ w, float* __restrict__ out) {
  const size_t row = blockIdx.x;
  const int t = threadIdx.x;
  f32x4 v = *(const f32x4*)&in[row * DMODEL + t * 4];
  float ss = block_sum256(v[0]*v[0] + v[1]*v[1] + v[2]*v[2] + v[3]*v[3]);
  float sc = rsqrtf(ss * (1.f / DMODEL) + 1e-5f);
  f32x4 wv = *(const f32x4*)&w[t * 4];
  f32x4 o;
  #pragma unroll
  for (int j = 0; j < 4; ++j) o[j] = v[j] * sc * wv[j];
  *(f32x4*)&out[row * DMODEL + t * 4] = o;
}

// ---------------- causal depthwise conv(4) + silu ----------------
__global__ __launch_bounds__(256) void conv_silu_k(
    const u16* __restrict__ xbc, const float* __restrict__ cw,
    const float* __restrict__ cb, u16* __restrict__ xact) {
  const int c = (blockIdx.x << 8) + threadIdx.x;
  const int b = blockIdx.y >> 8;
  const int t0 = (blockIdx.y & 255) << 3;
  const size_t rb = (size_t)b * SEQLEN + t0;
  const float w0 = cw[c*4], w1 = cw[c*4+1], w2 = cw[c*4+2], w3 = cw[c*4+3];
  const float bias = cb[c];
  const u16* src = xbc + c;
  float xm3 = t0 ? bf2f(src[(rb - 3) * XBCLD]) : 0.f;
  float xm2 = t0 ? bf2f(src[(rb - 2) * XBCLD]) : 0.f;
  float xm1 = t0 ? bf2f(src[(rb - 1) * XBCLD]) : 0.f;
  #pragma unroll
  for (int j = 0; j < 8; ++j) {
    float xc = bf2f(src[(rb + j) * XBCLD]);
    float a = bias + w0 * xm3 + w1 * xm2 + w2 * xm1 + w3 * xc;
    xact[(rb + j) * CONVDIM + c] = f2bf(a / (1.f + expf(-a)));
    xm3 = xm2; xm2 = xm1; xm1 = xc;
  }
}

// ================= SSD 3-phase (parallel over chunks) =================
// Phase A: per (b,h,ch): Y_local = P·X + D·x -> ybuf ; S^T[p][n] -> Sg ; et, decay.
__global__ __launch_bounds__(256, 2) void ssd_local_k(
    const u16* __restrict__ xact, const u16* __restrict__ XT,
    const u16* __restrict__ BT, const float* __restrict__ dtraw,
    const float* __restrict__ dt_bias, const float* __restrict__ A_log,
    const float* __restrict__ Dv, u16* __restrict__ ybuf,
    u16* __restrict__ Sg, float* __restrict__ etg, float* __restrict__ decayg) {
  __shared__ __align__(16) u16 Bs[64 * 128];
  __shared__ __align__(16) u16 U[128 * 64];   // Cs[64][128] (phase 1) -> BsT[128][64] (phase 3)
  __shared__ __align__(16) u16 Xt[32 * 64];
  __shared__ __align__(16) u16 Pl[64 * 64];
  __shared__ float cums[64], dts[64], fac[64];

  const int h = blockIdx.x, ch = blockIdx.y, b = blockIdx.z;
  const int tid = threadIdx.x, w = tid >> 6, l = tid & 63;
  const int l16 = l & 15, kg = l >> 4;
  const size_t tokb = (size_t)b * SEQLEN + (ch << 6);
  const size_t schunk = ((size_t)(b * 64 + h) << 5) + ch;

  // global loads (issue early)
  const int srow = tid >> 2, sseg = tid & 3;
  int4 creg[4], breg[4], btreg[4];
  #pragma unroll
  for (int i = 0; i < 4; ++i) {
    creg[i] = *(const int4*)&xact[(tokb + srow) * CONVDIM + 2176 + (sseg << 5) + (i << 3)];
    breg[i] = *(const int4*)&xact[(tokb + srow) * CONVDIM + 2048 + (sseg << 5) + (i << 3)];
  }
  const int xrow = tid >> 3, xseg = tid & 7;
  int4 xreg = *(const int4*)&XT[(size_t)((h << 5) + xrow) * NTOK + tokb + (xseg << 3)];
  #pragma unroll
  for (int i = 0; i < 4; ++i)
    btreg[i] = *(const int4*)&BT[(size_t)(tid >> 1) * NTOK + tokb + ((((tid & 1) << 2) + i) << 3)];

  // LDS stage (swizzled)
  #pragma unroll
  for (int i = 0; i < 4; ++i) {
    *(int4*)&U[swz128(srow, (sseg << 2) + i)]  = creg[i];
    *(int4*)&Bs[swz128(srow, (sseg << 2) + i)] = breg[i];
  }
  *(int4*)&Xt[swz64(xrow, xseg)] = xreg;

  if (w == 0) {
    float raw = dtraw[(tokb + l) * 64 + h] + dt_bias[h];
    float dtv = raw > 20.f ? raw : log1pf(__expf(raw));
    float cv = -dtv * __expf(A_log[h]);
    #pragma unroll
    for (int d = 1; d < 64; d <<= 1) {
      float o = __shfl_up(cv, d);
      if (l >= d) cv += o;
    }
    float a63 = __shfl(cv, 63);
    cums[l] = cv; dts[l] = dtv; fac[l] = dtv * __expf(a63 - cv);
    etg[(schunk << 6) + l] = __expf(cv);
    if (l == 0) decayg[schunk] = __expf(a63);
  }
  const float Dh = Dv[h];
  __syncthreads();                                   // (1)

  // G[t][s] = C·B^T (lower-tri tiles); wave w owns t-strip w
  f32x4 gacc[4] = {};
  #pragma unroll
  for (int ks = 0; ks < 4; ++ks) {
    bf16x8 ac = *(const bf16x8*)&U[swz128((w << 4) + l16, (ks << 2) + kg)];
    #pragma unroll
    for (int j = 0; j < 4; ++j)
      if (j <= w) {
        bf16x8 bb = *(const bf16x8*)&Bs[swz128((j << 4) + l16, (ks << 2) + kg)];
        gacc[j] = __builtin_amdgcn_mfma_f32_16x16x32_bf16(ac, bb, gacc[j], 0, 0, 0);
      }
  }
  // P[t][s] = G·exp(c_t - c_s)·dt_s for s<=t, else 0 (all 4 s-tiles written)
  float c_t[4];
  #pragma unroll
  for (int r = 0; r < 4; ++r) c_t[r] = cums[(w << 4) + (kg << 2) + r];
  #pragma unroll
  for (int j = 0; j < 4; ++j) {
    const int s = (j << 4) + l16;
    const float c_s = cums[s], d_s = dts[s];
    #pragma unroll
    for (int r = 0; r < 4; ++r) {
      const int t = (w << 4) + (kg << 2) + r;
      float v = (s <= t) ? gacc[j][r] * __expf(c_t[r] - c_s) * d_s : 0.f;
      Pl[(t << 6) + ((((s >> 3) ^ (t & 7)) << 3) | (s & 7))] = f2bf(v);
    }
  }

  // Y1 = P·X^T + D·x (wave reads only its own P strip; Xt staged pre-barrier)
  f32x4 y1[2] = {};
  const int nks = (w >> 1) + 1;
  for (int ks = 0; ks < nks; ++ks) {
    bf16x8 ap = *(const bf16x8*)&Pl[swz64((w << 4) + l16, (ks << 2) + kg)];
    #pragma unroll
    for (int pj = 0; pj < 2; ++pj) {
      bf16x8 bx = *(const bf16x8*)&Xt[swz64((pj << 4) + l16, (ks << 2) + kg)];
      y1[pj] = __builtin_amdgcn_mfma_f32_16x16x32_bf16(ap, bx, y1[pj], 0, 0, 0);
    }
  }
  #pragma unroll
  for (int r = 0; r < 4; ++r) {
    const int t = (w << 4) + (kg << 2) + r;
    #pragma unroll
    for (int pj = 0; pj < 2; ++pj) {
      const int p = (pj << 4) + l16;
      float xv = bf2f(Xt[(p << 6) + ((((t >> 3) ^ (p & 7)) << 3) | (t & 7))]);
      ybuf[(tokb + t) * DINNER + (h << 5) + p] = f2bf(y1[pj][r] + Dh * xv);
    }
  }

  __syncthreads();                                   // (2) Cs reads done -> overlay BsT
  #pragma unroll
  for (int i = 0; i < 4; ++i)
    *(int4*)&U[swz64(tid >> 1, ((tid & 1) << 2) + i)] = btreg[i];
  __syncthreads();                                   // (3) BsT visible

  // S^T[p][n] = Xsc^T·B ; wave w owns n in [32w, 32w+32)
  f32x4 sacc[2][2] = {};
  #pragma unroll
  for (int ks = 0; ks < 2; ++ks) {
    float f8[8];
    #pragma unroll
    for (int j = 0; j < 8; ++j) f8[j] = fac[(ks << 5) + (kg << 3) + j];
    #pragma unroll
    for (int pt = 0; pt < 2; ++pt) {
      bf16x8 xr = *(const bf16x8*)&Xt[swz64((pt << 4) + l16, (ks << 2) + kg)];
      bf16x8 xs;
      #pragma unroll
      for (int j = 0; j < 8; ++j) xs[j] = (__bf16)((float)xr[j] * f8[j]);
      #pragma unroll
      for (int nt = 0; nt < 2; ++nt) {
        bf16x8 bb = *(const bf16x8*)&U[swz64(((w << 1) + nt) * 16 + l16, (ks << 2) + kg)];
        sacc[pt][nt] = __builtin_amdgcn_mfma_f32_16x16x32_bf16(xs, bb, sacc[pt][nt], 0, 0, 0);
      }
    }
  }
  u16* sp = Sg + (schunk << 12);
  #pragma unroll
  for (int pt = 0; pt < 2; ++pt)
    #pragma unroll
    for (int nt = 0; nt < 2; ++nt)
      #pragma unroll
      for (int r = 0; r < 4; ++r) {
        const int pr = (pt << 4) + (kg << 2) + r;
        const int n = (w << 5) + (nt << 4) + l16;
        sp[(pr << 7) + n] = f2bf(sacc[pt][nt][r]);
      }
}

// Phase B: per (b,h): in-place scan. SH[ch] holds S on entry, H_prev on exit.
__global__ __launch_bounds__(256) void state_scan_k(
    u16* __restrict__ SH, const float* __restrict__ decayg) {
  const int bid = blockIdx.x;
  const size_t base = ((size_t)bid << 17) + ((size_t)threadIdx.x << 4);
  float acc[16] = {};
  u16x8 s0 = *(const u16x8*)&SH[base];
  u16x8 s1 = *(const u16x8*)&SH[base + 8];
  for (int ch = 0; ch < 32; ++ch) {
    const float d = decayg[(bid << 5) + ch];
    u16x8 n0 = {}, n1 = {};
    if (ch + 1 < 32) {
      n0 = *(const u16x8*)&SH[base + ((size_t)(ch + 1) << 12)];
      n1 = *(const u16x8*)&SH[base + ((size_t)(ch + 1) << 12) + 8];
    }
    u16x8 h0, h1;
    #pragma unroll
    for (int j = 0; j < 8; ++j) { h0[j] = f2bf(acc[j]); h1[j] = f2bf(acc[8 + j]); }
    *(u16x8*)&SH[base + ((size_t)ch << 12)] = h0;
    *(u16x8*)&SH[base + ((size_t)ch << 12) + 8] = h1;
    #pragma unroll
    for (int j = 0; j < 8; ++j) {
      acc[j]     = d * acc[j]     + bf2f(s0[j]);
      acc[8 + j] = d * acc[8 + j] + bf2f(s1[j]);
    }
    s0 = n0; s1 = n1;
  }
}

// Phase C: per (b,h,ch>=1): ybuf += exp(cums_t) · C·H_prev
__global__ __launch_bounds__(256) void ssd_cross_k(
    const u16* __restrict__ xact, const u16* __restrict__ Hg,
    const float* __restrict__ etg, u16* __restrict__ ybuf) {
  __shared__ __align__(16) u16 Cs[64 * 128];
  __shared__ __align__(16) u16 Hb[32 * 128];
  __shared__ float etl[64];
  const int h = blockIdx.x, ch = blockIdx.y + 1, b = blockIdx.z;
  const int tid = threadIdx.x, w = tid >> 6, l = tid & 63;
  const int l16 = l & 15, kg = l >> 4;
  const size_t tokb = (size_t)b * SEQLEN + (ch << 6);
  const size_t schunk = ((size_t)(b * 64 + h) << 5) + ch;

  const int srow = tid >> 2, sseg = tid & 3;
  #pragma unroll
  for (int i = 0; i < 4; ++i) {
    int4 v = *(const int4*)&xact[(tokb + srow) * CONVDIM + 2176 + (sseg << 5) + (i << 3)];
    *(int4*)&Cs[swz128(srow, (sseg << 2) + i)] = v;
  }
  const int hp = tid >> 3, hseg = tid & 7;
  #pragma unroll
  for (int i = 0; i < 2; ++i) {
    int4 v = *(const int4*)&Hg[(schunk << 12) + (hp << 7) + (((hseg << 1) + i) << 3)];
    *(int4*)&Hb[swz128(hp, (hseg << 1) + i)] = v;
  }
  if (tid < 64) etl[tid] = etg[(schunk << 6) + tid];
  __syncthreads();

  f32x4 y2[2] = {};
  #pragma unroll
  for (int ks = 0; ks < 4; ++ks) {
    bf16x8 ac = *(const bf16x8*)&Cs[swz128((w << 4) + l16, (ks << 2) + kg)];
    #pragma unroll
    for (int pj = 0; pj < 2; ++pj) {
      bf16x8 bh = *(const bf16x8*)&Hb[swz128((pj << 4) + l16, (ks << 2) + kg)];
      y2[pj] = __builtin_amdgcn_mfma_f32_16x16x32_bf16(ac, bh, y2[pj], 0, 0, 0);
    }
  }
  #pragma unroll
  for (int r = 0; r < 4; ++r) {
    const int t = (w << 4) + (kg << 2) + r;
    const float et = etl[t];
    #pragma unroll
    for (int pj = 0; pj < 2; ++pj) {
      const int p = (pj << 4) + l16;
      const size_t a = (tokb + t) * DINNER + (h << 5) + p;
      ybuf[a] = f2bf(bf2f(ybuf[a]) + et * y2[pj][r]);
    }
  }
}

// ---------------- legacy single-kernel SSD (fallback when ws is small) ----------------
__global__ __launch_bounds__(256) void ssd_k(
    const u16* __restrict__ xact, const u16* __restrict__ XT,
    const u16* __restrict__ BT, const float* __restrict__ dtraw,
    const float* __restrict__ dt_bias, const float* __restrict__ A_log,
    const float* __restrict__ Dv, u16* __restrict__ ybuf) {
  __shared__ __align__(16) u16 Cs[64 * 136];
  __shared__ __align__(16) u16 R1[128 * 72];
  __shared__ __align__(16) u16 Pl[64 * 72];
  __shared__ __align__(16) u16 Xt[32 * 72];
  __shared__ __align__(16) u16 Hb[32 * 136];
  __shared__ float cums[64], dts_l[64], fac[64];

  const int tid = threadIdx.x;
  const int w = tid >> 6, l = tid & 63, l16 = l & 15, kg = l >> 4;
  const int b = blockIdx.x >> 6, h = blockIdx.x & 63;
  const size_t rowb = (size_t)b * SEQLEN;
  const float expA = __expf(A_log[h]);
  const float bias = dt_bias[h];
  const float Dh = Dv[h];
  const int mi = w >> 1, njb = (w & 1) << 2;
  const int srow = tid >> 2, sseg = tid & 3;
  const int xrow = tid >> 3, xseg = tid & 7;

  f32x4 hacc[4] = {};

  for (int ch = 0; ch < NCH; ++ch) {
    const size_t tokb = rowb + ((size_t)ch << 6);
    int4 creg[4], breg[4];
    #pragma unroll
    for (int i = 0; i < 4; ++i) {
      creg[i] = *(const int4*)&xact[(tokb + srow) * CONVDIM + 2176 + (sseg << 5) + (i << 3)];
      breg[i] = *(const int4*)&xact[(tokb + srow) * CONVDIM + 2048 + (sseg << 5) + (i << 3)];
    }
    int4 xreg = *(const int4*)&XT[(size_t)(h * 32 + xrow) * NTOK + tokb + (xseg << 3)];
    float rawv = dtraw[(tokb + l) * 64 + h] + bias;
    float dtv = rawv > 20.f ? rawv : log1pf(__expf(rawv));
    float la = -dtv * expA;
    float cv = la;
    #pragma unroll
    for (int d = 1; d < 64; d <<= 1) {
      float o = __shfl_up(cv, d);
      if (l >= d) cv += o;
    }
    const float a63 = __shfl(cv, 63);

    __syncthreads();
    #pragma unroll
    for (int i = 0; i < 4; ++i) {
      *(int4*)&Cs[srow * 136 + (sseg << 5) + (i << 3)] = creg[i];
      *(int4*)&R1[srow * 136 + (sseg << 5) + (i << 3)] = breg[i];
    }
    *(int4*)&Xt[xrow * 72 + (xseg << 3)] = xreg;
    if (tid < 64) { cums[l] = cv; dts_l[l] = dtv; fac[l] = dtv * __expf(a63 - cv); }
    #pragma unroll
    for (int q = 0; q < 4; ++q)
      #pragma unroll
      for (int r = 0; r < 4; ++r)
        Hb[(mi * 16 + kg * 4 + r) * 136 + ((njb + q) << 4) + l16] = f2bf(hacc[q][r]);
    __syncthreads();

    f32x4 gacc[4] = {};
    #pragma unroll
    for (int ks = 0; ks < 4; ++ks) {
      bf16x8 ab = *(const bf16x8*)&R1[(w * 16 + l16) * 136 + (ks << 5) + (kg << 3)];
      #pragma unroll
      for (int j = 0; j < 4; ++j)
        if (j >= w) {
          bf16x8 bc = *(const bf16x8*)&Cs[(j * 16 + l16) * 136 + (ks << 5) + (kg << 3)];
          gacc[j] = __builtin_amdgcn_mfma_f32_16x16x32_bf16(ab, bc, gacc[j], 0, 0, 0);
        }
    }
    float c_s[4], d_s[4];
    #pragma unroll
    for (int r = 0; r < 4; ++r) {
      c_s[r] = cums[w * 16 + kg * 4 + r];
      d_s[r] = dts_l[w * 16 + kg * 4 + r];
    }
    #pragma unroll
    for (int j = 0; j < 4; ++j) {
      float c_t = cums[j * 16 + l16];
      #pragma unroll
      for (int r = 0; r < 4; ++r) {
        int s = w * 16 + kg * 4 + r, t = j * 16 + l16;
        float v = (s <= t) ? gacc[j][r] * __expf(c_t - c_s[r]) * d_s[r] : 0.f;
        Pl[t * 72 + s] = f2bf(v);
      }
    }
    __syncthreads();

    int4 btreg[4];
    #pragma unroll
    for (int i = 0; i < 4; ++i) {
      int sl = ((tid & 1) << 2) + i;
      btreg[i] = *(const int4*)&BT[(size_t)(tid >> 1) * NTOK + tokb + (sl << 3)];
    }

    f32x4 y1[2] = {}, y2[2] = {};
    const int nks = (w >= 2) ? 2 : 1;
    for (int ks = 0; ks < nks; ++ks) {
      bf16x8 ap = *(const bf16x8*)&Pl[(w * 16 + l16) * 72 + (ks << 5) + (kg << 3)];
      #pragma unroll
      for (int pj = 0; pj < 2; ++pj) {
        bf16x8 bx = *(const bf16x8*)&Xt[(pj * 16 + l16) * 72 + (ks << 5) + (kg << 3)];
        y1[pj] = __builtin_amdgcn_mfma_f32_16x16x32_bf16(ap, bx, y1[pj], 0, 0, 0);
      }
    }
    #pragma unroll
    for (int ks = 0; ks < 4; ++ks) {
      bf16x8 ac = *(const bf16x8*)&Cs[(w * 16 + l16) * 136 + (ks << 5) + (kg << 3)];
      #pragma unroll
      for (int pj = 0; pj < 2; ++pj) {
        bf16x8 bh = *(const bf16x8*)&Hb[(pj * 16 + l16) * 136 + (ks << 5) + (kg << 3)];
        y2[pj] = __builtin_amdgcn_mfma_f32_16x16x32_bf16(ac, bh, y2[pj], 0, 0, 0);
      }
    }
    #pragma unroll
    for (int r = 0; r < 4; ++r) {
      const int t = w * 16 + kg * 4 + r;
      const float et = __expf(cums[t]);
      #pragma unroll
      for (int pj = 0; pj < 2; ++pj) {
        const int p = pj * 16 + l16;
        float xv = bf2f(Xt[p * 72 + t]);
        float yv = y1[pj][r] + et * y2[pj][r] + Dh * xv;
        ybuf[(tokb + t) * DINNER + (h << 5) + p] = f2bf(yv);
      }
    }
    __syncthreads();

    #pragma unroll
    for (int i = 0; i < 4; ++i) {
      int sl = ((tid & 1) << 2) + i;
      *(int4*)&R1[(tid >> 1) * 72 + (sl << 3)] = btreg[i];
    }
    {
      bf16x8 xv = *(const bf16x8*)&Xt[xrow * 72 + (xseg << 3)];
      u16x8 xo;
      #pragma unroll
      for (int jj = 0; jj < 8; ++jj)
        xo[jj] = f2bf((float)xv[jj] * fac[(xseg << 3) + jj]);
      *(u16x8*)&Xt[xrow * 72 + (xseg << 3)] = xo;
    }
    __syncthreads();

    const float g63 = __expf(a63);
    #pragma unroll
    for (int q = 0; q < 4; ++q)
      #pragma unroll
      for (int r = 0; r < 4; ++r) hacc[q][r] *= g63;
    #pragma unroll
    for (int ks = 0; ks < 2; ++ks) {
      bf16x8 ax = *(const bf16x8*)&Xt[(mi * 16 + l16) * 72 + (ks << 5) + (kg << 3)];
      #pragma unroll
      for (int q = 0; q < 4; ++q) {
        bf16x8 bb = *(const bf16x8*)&R1[(((njb + q) << 4) + l16) * 72 + (ks << 5) + (kg << 3)];
        hacc[q] = __builtin_amdgcn_mfma_f32_16x16x32_bf16(ax, bb, hacc[q], 0, 0, 0);
      }
    }
  }
}

// ---------------- gated RMSNorm in place ----------------
__global__ __launch_bounds__(256) void gate_rmsnorm_k(
    const u16* __restrict__ y, u16* __restrict__ zy, const float* __restrict__ gw) {
  const size_t row = blockIdx.x;
  const int t = threadIdx.x;
  bf16x8 yv = *(const bf16x8*)&y[row * DINNER + t * 8];
  bf16x8 zv = *(const bf16x8*)&zy[row * DINNER + t * 8];
  float val[8]; float ss = 0.f;
  #pragma unroll
  for (int j = 0; j < 8; ++j) {
    float z = (float)zv[j];
    float v = (float)yv[j] * (z / (1.f + expf(-z)));
    val[j] = v; ss += v * v;
  }
  ss = block_sum256(ss);
  float sc = rsqrtf(ss * (1.f / DINNER) + 1e-5f);
  ushort4 o0, o1;
  o0.x = f2bf(val[0]*sc*gw[t*8+0]); o0.y = f2bf(val[1]*sc*gw[t*8+1]);
  o0.z = f2bf(val[2]*sc*gw[t*8+2]); o0.w = f2bf(val[3]*sc*gw[t*8+3]);
  o1.x = f2bf(val[4]*sc*gw[t*8+4]); o1.y = f2bf(val[5]*sc*gw[t*8+5]);
  o1.z = f2bf(val[6]*sc*gw[t*8+6]); o1.w = f2bf(val[7]*sc*gw[t*8+7]);
  *(ushort4*)&zy[row * DINNER + t * 8] = o0;
  *(ushort4*)&zy[row * DINNER + t * 8 + 4] = o1;
}

extern "C" void kernel_launch(void* const* d_in, const int* in_sizes, int n_in,
                              void* d_out, int out_size, void* d_ws, size_t ws_size,
                              hipStream_t stream) {
  const float* x       = (const float*)d_in[0];
  const float* W_in    = (const float*)d_in[1];
  const float* conv_w  = (const float*)d_in[2];
  const float* conv_b  = (const float*)d_in[3];
  const float* dt_bias = (const float*)d_in[4];
  const float* A_log   = (const float*)d_in[5];
  const float* Dv      = (const float*)d_in[6];
  const float* gate_w  = (const float*)d_in[7];
  const float* W_out   = (const float*)d_in[8];
  const float* block_w = (const float*)d_in[9];
  const float* final_w = (const float*)d_in[10];
  float* out = (float*)d_out;

  char* p = (char*)d_ws;
  auto alloc = [&](size_t bytes) { char* r = p; p += (bytes + 255) & ~(size_t)255; return r; };
  float* hbuf  = (float*)alloc((size_t)NTOK * DMODEL * 4);
  u16*   slabA = (u16*)  alloc((size_t)NTOK * DINNER * 2);    // hn / ybuf
  u16*   slabB = (u16*)  alloc((size_t)NTOK * DINNER * 2);    // zy (gate in place)
  u16*   slabC = (u16*)  alloc((size_t)NTOK * CONVDIM * 2);   // wt / xact
  u16*   xbcXT = (u16*)  alloc((size_t)NTOK * XBCLD * 2);     // xbc -> XT overlay
  float* dtraw = (float*)alloc((size_t)NTOK * NHEADS * 4);
  u16*   BT    = (u16*)  alloc((size_t)128 * NTOK * 2);
  if ((size_t)(p - (char*)d_ws) > ws_size) return;  // zero output signature: absmax ~5.47

  // parallel-SSD extra buffers (used only if they fit)
  u16*   Sg     = (u16*)  alloc((size_t)BATCH * NHEADS * NCH * 4096 * 2);  // 64 MB
  float* etg    = (float*)alloc((size_t)BATCH * NHEADS * NCH * 64 * 4);    // 2 MB
  float* decayg = (float*)alloc((size_t)BATCH * NHEADS * NCH * 4);
  const bool par = ((size_t)(p - (char*)d_ws) <= ws_size);

  u16* hn   = slabA;
  u16* ybuf = slabA;
  u16* wt   = slabC;
  u16* xact = slabC;
  u16* xbc  = xbcXT;
  u16* XT   = xbcXT;   // overlays xbc after conv

  copy_k<<<2048, 256, 0, stream>>>(x, hbuf, NTOK * DMODEL / 4);

  for (int l = 0; l < NLAYER; ++l) {
    rmsnorm_bf16_k<<<NTOK, 256, 0, stream>>>(hbuf, block_w + l * DMODEL, hn);
    transpose_cvt_k<<<dim3(DPROJP/64, DMODEL/64), 256, 0, stream>>>(
        W_in + (size_t)l * DMODEL * DPROJ, wt, DMODEL, DPROJ, DPROJP);
    gemm_bf16_k<1><<<dim3(DPROJP/128, NTOK/128), 256, 0, stream>>>(
        hn, wt, nullptr, slabB, xbc, dtraw, DMODEL);
    conv_silu_k<<<dim3(CONVDIM/256, BATCH * SEQLEN / 8), 256, 0, stream>>>(
        xbc, conv_w + (size_t)l * CONVDIM * 4, conv_b + (size_t)l * CONVDIM, xact);
    transpose_bf16_k<<<dim3(DINNER/64, NTOK/64), 256, 0, stream>>>(xact, XT);
    transpose_bf16_k<<<dim3(2, NTOK/64), 256, 0, stream>>>(xact + DINNER, BT);
    if (par) {
      ssd_local_k<<<dim3(NHEADS, NCH, BATCH), 256, 0, stream>>>(
          xact, XT, BT, dtraw, dt_bias + l * NHEADS, A_log + l * NHEADS,
          Dv + l * NHEADS, ybuf, Sg, etg, decayg);
      state_scan_k<<<BATCH * NHEADS, 256, 0, stream>>>(Sg, decayg);
      ssd_cross_k<<<dim3(NHEADS, NCH - 1, BATCH), 256, 0, stream>>>(
          xact, Sg, etg, ybuf);
    } else {
      ssd_k<<<BATCH * NHEADS, 256, 0, stream>>>(
          xact, XT, BT, dtraw, dt_bias + l * NHEADS, A_log + l * NHEADS,
          Dv + l * NHEADS, ybuf);
    }
    gate_rmsnorm_k<<<NTOK, 256, 0, stream>>>(ybuf, slabB, gate_w + (size_t)l * DINNER);
    transpose_cvt_k<<<dim3(DMODEL/64, DINNER/64), 256, 0, stream>>>(
        W_out + (size_t)l * DINNER * DMODEL, wt, DINNER, DMODEL, DMODEL);
    gemm_bf16_k<0><<<dim3(DMODEL/128, NTOK/128), 256, 0, stream>>>(
        slabB, wt, hbuf, nullptr, nullptr, nullptr, DINNER);
  }
  final_rmsnorm_k<<<NTOK, 256, 0, stream>>>(hbuf, final_w, out);
}